// Round 15
// baseline (4541.999 us; speedup 1.0000x reference)
//
#include <hip/hip_runtime.h>
#include <cstdint>

#define B_ROWS 65536
#define D_IN   640
#define D_LAT  2560
#define K_SEL  32
#define NCAND  48      // minimum candidates (threshold targets count in [48,64])
#define CCAP   64      // candidate capacity per row
// np-exact K-panel boundaries (OpenBLAS SKYLAKEX Q=192): 192+192+128+128
#define P1 192
#define P2 384
#define P3 512
#define WB   12        // candidate rows staged per batch
#define WSTR 642       // LDS row stride in floats: bank = 2c+i (cands conflict-free)

typedef __attribute__((ext_vector_type(8))) short short8;
typedef __attribute__((ext_vector_type(4))) float f32x4;

static __device__ __forceinline__ ushort f2bf(float f) {
    uint32_t u = __float_as_uint(f);
    u += 0x7fffu + ((u >> 16) & 1u);   // round-to-nearest-even
    return (ushort)(u >> 16);
}

// ---------------- generic fp32 -> bf16 convert (4 elems/thread) -------------------
__global__ __launch_bounds__(256) void cvt_bf16(const float* __restrict__ src,
                                                ushort* __restrict__ dst) {
    const size_t i = ((size_t)blockIdx.x * 256 + threadIdx.x) * 4;
    float4 v = *(const float4*)(src + i);
    ushort4 o;
    o.x = f2bf(v.x); o.y = f2bf(v.y); o.z = f2bf(v.z); o.w = f2bf(v.w);
    *(ushort4*)(dst + i) = o;
}

// ---------------- W_dec transpose: [640][2560] -> WdT [2560][640] ----------------
__global__ __launch_bounds__(256) void transpose_wdec(const float* __restrict__ Wd,
                                                      float* __restrict__ WdT) {
    __shared__ float t[32][33];
    const int j0 = blockIdx.x * 32;
    const int i0 = blockIdx.y * 32;
    const int tx = threadIdx.x & 31, ty = threadIdx.x >> 5;
#pragma unroll
    for (int q = 0; q < 4; ++q)
        t[ty + 8 * q][tx] = Wd[(size_t)(i0 + ty + 8 * q) * D_LAT + j0 + tx];
    __syncthreads();
#pragma unroll
    for (int q = 0; q < 4; ++q)
        WdT[(size_t)(j0 + ty + 8 * q) * D_IN + i0 + tx] = t[tx][ty + 8 * q];
}

// ---------------- bf16 MFMA filter GEMM (both operands pre-converted) ------------
__global__ __launch_bounds__(256, 2) void enc_mfma(const ushort* __restrict__ A,
                                                   const ushort* __restrict__ Wb,
                                                   const float* __restrict__ bias,
                                                   float* __restrict__ C) {
    __shared__ ushort Al[128][40];   // pad 32->40 (80B row): 2-way conflicts = free
    __shared__ ushort Bl[128][40];
    const int tid = threadIdx.x;
    const int n0 = blockIdx.x * 128;
    const int m0 = blockIdx.y * 128;
    const int srow = tid >> 1, shalf = tid & 1;
    const ushort* Ap = A  + (size_t)(m0 + srow) * D_IN + shalf * 16;
    const ushort* Bp = Wb + (size_t)(n0 + srow) * D_IN + shalf * 16;

    const int w = tid >> 6, l = tid & 63;
    const int wm = w >> 1, wn = w & 1;
    const int fr = l & 15, ko = l >> 4;

    f32x4 acc[4][4];
#pragma unroll
    for (int i = 0; i < 4; ++i)
#pragma unroll
        for (int j = 0; j < 4; ++j) acc[i][j] = (f32x4)0.0f;

    uint4 a0, a1, b0, b1;
#define LOADT(KT)                                                    \
    {                                                                \
        const uint* ap = (const uint*)(Ap + (KT) * 32);              \
        a0 = *(const uint4*)(ap);                                    \
        a1 = *(const uint4*)(ap + 4);                                \
        const uint* bp = (const uint*)(Bp + (KT) * 32);              \
        b0 = *(const uint4*)(bp);                                    \
        b1 = *(const uint4*)(bp + 4);                                \
    }

    LOADT(0);
    const int NT = D_IN / 32;   // 20
    for (int kt = 0; kt < NT; ++kt) {
        *(uint4*)&Al[srow][shalf * 16]     = a0;
        *(uint4*)&Al[srow][shalf * 16 + 8] = a1;
        *(uint4*)&Bl[srow][shalf * 16]     = b0;
        *(uint4*)&Bl[srow][shalf * 16 + 8] = b1;
        __syncthreads();
        if (kt + 1 < NT) LOADT(kt + 1);

        short8 af[4], bf[4];
#pragma unroll
        for (int fm = 0; fm < 4; ++fm)
            af[fm] = *(const short8*)&Al[wm * 64 + fm * 16 + fr][ko * 8];
#pragma unroll
        for (int fn = 0; fn < 4; ++fn)
            bf[fn] = *(const short8*)&Bl[wn * 64 + fn * 16 + fr][ko * 8];
#pragma unroll
        for (int fm = 0; fm < 4; ++fm)
#pragma unroll
            for (int fn = 0; fn < 4; ++fn)
                acc[fm][fn] = __builtin_amdgcn_mfma_f32_16x16x32_bf16(
                    af[fm], bf[fn], acc[fm][fn], 0, 0, 0);
        __syncthreads();
    }
#undef LOADT

#pragma unroll
    for (int fn = 0; fn < 4; ++fn) {
        const int col = n0 + wn * 64 + fn * 16 + fr;
        const float bb = bias[col];
#pragma unroll
        for (int fm = 0; fm < 4; ++fm) {
#pragma unroll
            for (int j = 0; j < 4; ++j) {
                const int row = m0 + wm * 64 + fm * 16 + ko * 4 + j;
                C[(size_t)row * D_LAT + col] = acc[fm][fn][j] + bb;
            }
        }
    }
}

// ---------------- Candidate select by threshold (wave-per-row) -------------------
__global__ __launch_bounds__(256) void topk_cand(const float* __restrict__ lat,
                                                 int* __restrict__ cidx,
                                                 int* __restrict__ ccnt) {
    const int wv = threadIdx.x >> 6, lane = threadIdx.x & 63;
    const int r = blockIdx.x * 4 + wv;
    const float* row = lat + (size_t)r * D_LAT;

    float4 v[10];
#pragma unroll
    for (int e = 0; e < 10; ++e)
        v[e] = *(const float4*)(row + e * 256 + lane * 4);

    float mx = v[0].x;
#pragma unroll
    for (int e = 0; e < 10; ++e) {
        mx = fmaxf(mx, fmaxf(fmaxf(v[e].x, v[e].y), fmaxf(v[e].z, v[e].w)));
    }
#pragma unroll
    for (int off = 1; off < 64; off <<= 1) mx = fmaxf(mx, __shfl_xor(mx, off));

    auto countGt = [&](float t) -> int {
        int c = 0;
#pragma unroll
        for (int e = 0; e < 10; ++e)
            c += (v[e].x > t) + (v[e].y > t) + (v[e].z > t) + (v[e].w > t);
#pragma unroll
        for (int off = 1; off < 64; off <<= 1) c += __shfl_xor(c, off);
        return c;
    };

    float lo = mx - 2.0f;
    int clo = countGt(lo);
    if (clo < NCAND) { lo = mx - 4.0f; clo = countGt(lo); }
    if (clo < NCAND) { lo = mx - 16.0f; clo = countGt(lo); }   // paranoia tier
    float hi = mx;                                             // count(>mx)=0
    for (int it = 0; it < 28 && clo > CCAP; ++it) {
        const float mid = 0.5f * (lo + hi);
        const int c = countGt(mid);
        if (c >= NCAND) { lo = mid; clo = c; } else hi = mid;
    }

    int base = 0;
#pragma unroll
    for (int e = 0; e < 10; ++e) {
#pragma unroll
        for (int q = 0; q < 4; ++q) {
            const float val = (q == 0) ? v[e].x : (q == 1) ? v[e].y
                            : (q == 2) ? v[e].z : v[e].w;
            const bool take = val > lo;
            const uint64_t m = __ballot(take);
            const int pos = base + __popcll(m & ((1ull << lane) - 1ull));
            if (take && pos < CCAP)
                cidx[(size_t)r * CCAP + pos] = e * 256 + lane * 4 + q;
            base += __popcll(m);
        }
    }
    if (lane == 0) ccnt[r] = (base < CCAP) ? base : CCAP;
}

// ---------------- Exact refine: LDS-staged gathers, lane = (candidate, panel) ----
// Batch WB=12 candidate W-rows staged cooperatively (coalesced float2 wave loads
// -> streamed L2 lines, fixing the random-64B-request bottleneck), chains read
// from LDS. Per-panel fp32 fmaf chain, k ascending; combine ((a0+a1)+a2)+a3 +
// bias -> bit-exact np values; top-32 ties -> lower index.
__global__ __launch_bounds__(256, 4) void refine_exact(const float* __restrict__ x,
                                                       const float* __restrict__ We,
                                                       const float* __restrict__ be,
                                                       const int* __restrict__ cidx,
                                                       const int* __restrict__ ccnt,
                                                       float* __restrict__ sparse,
                                                       float* __restrict__ vals,
                                                       int* __restrict__ idxs) {
    const int tid = threadIdx.x;
    const int r = blockIdx.x;

    __shared__ float xs[D_IN];
    __shared__ float wbuf[WB * WSTR];
    __shared__ int   scidx[CCAP];
    __shared__ float pv[CCAP][4];
    __shared__ int   selj[CCAP];
    __shared__ float selv[CCAP];

    const int cnt = ccnt[r];
    for (int i = tid; i < D_IN; i += 256) xs[i] = x[(size_t)r * D_IN + i];
    if (tid < CCAP) scidx[tid] = (tid < cnt) ? cidx[(size_t)r * CCAP + tid] : 0;
    __syncthreads();

    const int cl = tid >> 2, p = tid & 3;   // compute mapping: threads 0..47
    const int nb = (cnt + WB - 1) / WB;
    for (int b = 0; b < nb; ++b) {
        const int c0 = b * WB;
        // ---- stage WB rows, coalesced float2 (512B contiguous per wave-instr)
        for (int t = tid; t < WB * (D_IN / 2); t += 256) {
            const int row = t / (D_IN / 2), off = t % (D_IN / 2);
            const int cg = c0 + row;
            const int j = (cg < cnt) ? scidx[cg] : scidx[0];
            const float2 v = *(const float2*)(We + (size_t)j * D_IN + off * 2);
            *(float2*)&wbuf[row * WSTR + off * 2] = v;
        }
        __syncthreads();
        // ---- chains out of LDS
        if (tid < WB * 4) {
            const int c = c0 + cl;
            if (c < cnt) {
                const int k0 = (p == 0) ? 0  : (p == 1) ? P1 : (p == 2) ? P2 : P3;
                const int k1 = (p == 0) ? P1 : (p == 1) ? P2 : (p == 2) ? P3 : D_IN;
                const float* wr = &wbuf[cl * WSTR];
                float a = 0.f;
#pragma unroll 8
                for (int i = k0; i < k1; i += 2) {
                    const float2 wv = *(const float2*)(wr + i);   // ds_read_b64
                    const float2 xv = *(const float2*)(&xs[i]);   // broadcast
                    a = fmaf(wv.x, xv.x, a);
                    a = fmaf(wv.y, xv.y, a);
                }
                pv[c][p] = a;
            }
        }
        __syncthreads();
    }

    const int wv = tid >> 6, lane = tid & 63;
    if (wv == 0) {
        const float NEGINF = -__builtin_inff();
        float mv = NEGINF; int mi = 0x7fffffff;
        float val = 0.f; int j = 0;
        if (lane < cnt) {
            j = scidx[lane];
            val = (((pv[lane][0] + pv[lane][1]) + pv[lane][2]) + pv[lane][3]) + be[j];
            mv = val; mi = j;
        }
        bool selected = false;
        for (int t = 0; t < K_SEL; ++t) {
            float bv = mv; int bi = mi;
#pragma unroll
            for (int off = 1; off < 64; off <<= 1) {
                float ov = __shfl_xor(bv, off);
                int   oi = __shfl_xor(bi, off);
                if (ov > bv || (ov == bv && oi < bi)) { bv = ov; bi = oi; }
            }
            if (lane == 0) {
                vals[(size_t)r * K_SEL + t] = bv;
                idxs[(size_t)r * K_SEL + t] = bi;
            }
            if (bi == mi) {       // winner lane (candidate indices unique)
                selected = true;
                mv = NEGINF; mi = 0x7fffffff;
            }
        }
        selj[lane] = selected ? j : -1;
        selv[lane] = val;
    }
    __syncthreads();

    float4 z; z.x = z.y = z.z = z.w = 0.f;
    float4* srow4 = (float4*)(sparse + (size_t)r * D_LAT);
    for (int p2 = tid; p2 < D_LAT / 4; p2 += 256) srow4[p2] = z;
    __syncthreads();
    if (tid < CCAP) {
        const int jj = selj[tid];
        if (jj >= 0) sparse[(size_t)r * D_LAT + jj] = selv[tid];
    }
}

// ---------------- Decoder: recon[r] = sum_k vals[r][k] * WdT[idx[r][k]][:] + b_dec
__global__ __launch_bounds__(256) void dec_kernel(const float* __restrict__ vals,
                                                  const int* __restrict__ idxs,
                                                  const float* __restrict__ WdT,
                                                  const float* __restrict__ bdec,
                                                  float* __restrict__ recon) {
    const int wave = threadIdx.x >> 6, lane = threadIdx.x & 63;
    const int r = blockIdx.x * 4 + wave;

    float lv = 0.f; int li = 0;
    if (lane < K_SEL) {
        lv = vals[(size_t)r * K_SEL + lane];
        li = idxs[(size_t)r * K_SEL + lane];
    }
    float acc[10];
#pragma unroll
    for (int e = 0; e < 10; ++e) acc[e] = bdec[lane + e * 64];

#pragma unroll 4
    for (int k = 0; k < K_SEL; ++k) {
        float vkv = __shfl(lv, k);
        int   jj  = __shfl(li, k);
        const float* wr = WdT + (size_t)jj * D_IN + lane;
#pragma unroll
        for (int e = 0; e < 10; ++e) acc[e] = fmaf(vkv, wr[e * 64], acc[e]);
    }
    float* out = recon + (size_t)r * D_IN + lane;
#pragma unroll
    for (int e = 0; e < 10; ++e) out[e * 64] = acc[e];
}

extern "C" void kernel_launch(void* const* d_in, const int* in_sizes, int n_in,
                              void* d_out, int out_size, void* d_ws, size_t ws_size,
                              hipStream_t stream) {
    const float* x     = (const float*)d_in[0];
    const float* W_enc = (const float*)d_in[1];
    const float* b_enc = (const float*)d_in[2];
    const float* W_dec = (const float*)d_in[3];
    const float* b_dec = (const float*)d_in[4];

    float* recon  = (float*)d_out;                                  // [B][640]
    float* sparse = (float*)d_out + (size_t)B_ROWS * D_IN;          // [B][2560]

    // xB (bf16 copy of x, 84MB) parks in the recon region (167MB): recon is only
    // written by dec_kernel, which runs after enc_mfma has consumed xB.
    ushort* xB = (ushort*)recon;

    char* ws = (char*)d_ws;
    size_t off = 0;
    float*  WdT  = (float*) (ws + off); off += (size_t)D_LAT * D_IN * 4;    // 6.55 MB
    ushort* WeB  = (ushort*)(ws + off); off += (size_t)D_LAT * D_IN * 2;    // 3.28 MB
    int*    cidx = (int*)   (ws + off); off += (size_t)B_ROWS * CCAP * 4;   // 16.8 MB
    int*    ccnt = (int*)   (ws + off); off += (size_t)B_ROWS * 4;          // 0.26 MB
    float*  vals = (float*) (ws + off); off += (size_t)B_ROWS * K_SEL * 4;  // 8.4 MB
    int*    idxs = (int*)   (ws + off);                                     // 8.4 MB

    hipLaunchKernelGGL(cvt_bf16, dim3((size_t)B_ROWS * D_IN / 1024), dim3(256), 0, stream,
                       x, xB);
    hipLaunchKernelGGL(cvt_bf16, dim3((size_t)D_LAT * D_IN / 1024), dim3(256), 0, stream,
                       W_enc, WeB);
    hipLaunchKernelGGL(transpose_wdec, dim3(D_LAT / 32, D_IN / 32), dim3(256), 0, stream,
                       W_dec, WdT);
    hipLaunchKernelGGL(enc_mfma, dim3(D_LAT / 128, B_ROWS / 128), dim3(256), 0, stream,
                       xB, WeB, b_enc, sparse);
    hipLaunchKernelGGL(topk_cand, dim3(B_ROWS / 4), dim3(256), 0, stream,
                       sparse, cidx, ccnt);
    hipLaunchKernelGGL(refine_exact, dim3(B_ROWS), dim3(256), 0, stream,
                       x, W_enc, b_enc, cidx, ccnt, sparse, vals, idxs);
    hipLaunchKernelGGL(dec_kernel, dim3(B_ROWS / 4), dim3(256), 0, stream,
                       vals, idxs, WdT, b_dec, recon);
}

// Round 16
// 2595.904 us; speedup vs baseline: 1.7497x; 1.7497x over previous
//
#include <hip/hip_runtime.h>
#include <cstdint>

#define B_ROWS 65536
#define D_IN   640
#define D_LAT  2560
#define K_SEL  32
#define NCAND  48      // minimum candidates (threshold targets count in [48,64])
#define CCAP   64      // candidate capacity per row
// np-exact K-panel boundaries (OpenBLAS SKYLAKEX Q=192): 192+192+128+128
#define P1 192
#define P2 384
#define P3 512

typedef __attribute__((ext_vector_type(8))) short short8;
typedef __attribute__((ext_vector_type(4))) float f32x4;

static __device__ __forceinline__ ushort f2bf(float f) {
    uint32_t u = __float_as_uint(f);
    u += 0x7fffu + ((u >> 16) & 1u);   // round-to-nearest-even
    return (ushort)(u >> 16);
}

// ---------------- generic fp32 -> bf16 convert (4 elems/thread) -------------------
__global__ __launch_bounds__(256) void cvt_bf16(const float* __restrict__ src,
                                                ushort* __restrict__ dst) {
    const size_t i = ((size_t)blockIdx.x * 256 + threadIdx.x) * 4;
    float4 v = *(const float4*)(src + i);
    ushort4 o;
    o.x = f2bf(v.x); o.y = f2bf(v.y); o.z = f2bf(v.z); o.w = f2bf(v.w);
    *(ushort4*)(dst + i) = o;
}

// ---------------- W_dec transpose: [640][2560] -> WdT [2560][640] ----------------
__global__ __launch_bounds__(256) void transpose_wdec(const float* __restrict__ Wd,
                                                      float* __restrict__ WdT) {
    __shared__ float t[32][33];
    const int j0 = blockIdx.x * 32;
    const int i0 = blockIdx.y * 32;
    const int tx = threadIdx.x & 31, ty = threadIdx.x >> 5;
#pragma unroll
    for (int q = 0; q < 4; ++q)
        t[ty + 8 * q][tx] = Wd[(size_t)(i0 + ty + 8 * q) * D_LAT + j0 + tx];
    __syncthreads();
#pragma unroll
    for (int q = 0; q < 4; ++q)
        WdT[(size_t)(j0 + ty + 8 * q) * D_IN + i0 + tx] = t[tx][ty + 8 * q];
}

// ---------------- bf16 MFMA filter GEMM (both operands pre-converted) ------------
__global__ __launch_bounds__(256, 2) void enc_mfma(const ushort* __restrict__ A,
                                                   const ushort* __restrict__ Wb,
                                                   const float* __restrict__ bias,
                                                   float* __restrict__ C) {
    __shared__ ushort Al[128][40];   // pad 32->40 (80B row): 2-way conflicts = free
    __shared__ ushort Bl[128][40];
    const int tid = threadIdx.x;
    const int n0 = blockIdx.x * 128;
    const int m0 = blockIdx.y * 128;
    const int srow = tid >> 1, shalf = tid & 1;
    const ushort* Ap = A  + (size_t)(m0 + srow) * D_IN + shalf * 16;
    const ushort* Bp = Wb + (size_t)(n0 + srow) * D_IN + shalf * 16;

    const int w = tid >> 6, l = tid & 63;
    const int wm = w >> 1, wn = w & 1;
    const int fr = l & 15, ko = l >> 4;

    f32x4 acc[4][4];
#pragma unroll
    for (int i = 0; i < 4; ++i)
#pragma unroll
        for (int j = 0; j < 4; ++j) acc[i][j] = (f32x4)0.0f;

    uint4 a0, a1, b0, b1;
#define LOADT(KT)                                                    \
    {                                                                \
        const uint* ap = (const uint*)(Ap + (KT) * 32);              \
        a0 = *(const uint4*)(ap);                                    \
        a1 = *(const uint4*)(ap + 4);                                \
        const uint* bp = (const uint*)(Bp + (KT) * 32);              \
        b0 = *(const uint4*)(bp);                                    \
        b1 = *(const uint4*)(bp + 4);                                \
    }

    LOADT(0);
    const int NT = D_IN / 32;   // 20
    for (int kt = 0; kt < NT; ++kt) {
        *(uint4*)&Al[srow][shalf * 16]     = a0;
        *(uint4*)&Al[srow][shalf * 16 + 8] = a1;
        *(uint4*)&Bl[srow][shalf * 16]     = b0;
        *(uint4*)&Bl[srow][shalf * 16 + 8] = b1;
        __syncthreads();
        if (kt + 1 < NT) LOADT(kt + 1);

        short8 af[4], bf[4];
#pragma unroll
        for (int fm = 0; fm < 4; ++fm)
            af[fm] = *(const short8*)&Al[wm * 64 + fm * 16 + fr][ko * 8];
#pragma unroll
        for (int fn = 0; fn < 4; ++fn)
            bf[fn] = *(const short8*)&Bl[wn * 64 + fn * 16 + fr][ko * 8];
#pragma unroll
        for (int fm = 0; fm < 4; ++fm)
#pragma unroll
            for (int fn = 0; fn < 4; ++fn)
                acc[fm][fn] = __builtin_amdgcn_mfma_f32_16x16x32_bf16(
                    af[fm], bf[fn], acc[fm][fn], 0, 0, 0);
        __syncthreads();
    }
#undef LOADT

#pragma unroll
    for (int fn = 0; fn < 4; ++fn) {
        const int col = n0 + wn * 64 + fn * 16 + fr;
        const float bb = bias[col];
#pragma unroll
        for (int fm = 0; fm < 4; ++fm) {
#pragma unroll
            for (int j = 0; j < 4; ++j) {
                const int row = m0 + wm * 64 + fm * 16 + ko * 4 + j;
                C[(size_t)row * D_LAT + col] = acc[fm][fn][j] + bb;
            }
        }
    }
}

// ---------------- Candidate select by threshold (wave-per-row) -------------------
__global__ __launch_bounds__(256) void topk_cand(const float* __restrict__ lat,
                                                 int* __restrict__ cidx,
                                                 int* __restrict__ ccnt) {
    const int wv = threadIdx.x >> 6, lane = threadIdx.x & 63;
    const int r = blockIdx.x * 4 + wv;
    const float* row = lat + (size_t)r * D_LAT;

    float4 v[10];
#pragma unroll
    for (int e = 0; e < 10; ++e)
        v[e] = *(const float4*)(row + e * 256 + lane * 4);

    float mx = v[0].x;
#pragma unroll
    for (int e = 0; e < 10; ++e) {
        mx = fmaxf(mx, fmaxf(fmaxf(v[e].x, v[e].y), fmaxf(v[e].z, v[e].w)));
    }
#pragma unroll
    for (int off = 1; off < 64; off <<= 1) mx = fmaxf(mx, __shfl_xor(mx, off));

    auto countGt = [&](float t) -> int {
        int c = 0;
#pragma unroll
        for (int e = 0; e < 10; ++e)
            c += (v[e].x > t) + (v[e].y > t) + (v[e].z > t) + (v[e].w > t);
#pragma unroll
        for (int off = 1; off < 64; off <<= 1) c += __shfl_xor(c, off);
        return c;
    };

    float lo = mx - 2.0f;
    int clo = countGt(lo);
    if (clo < NCAND) { lo = mx - 4.0f; clo = countGt(lo); }
    if (clo < NCAND) { lo = mx - 16.0f; clo = countGt(lo); }   // paranoia tier
    float hi = mx;                                             // count(>mx)=0
    for (int it = 0; it < 28 && clo > CCAP; ++it) {
        const float mid = 0.5f * (lo + hi);
        const int c = countGt(mid);
        if (c >= NCAND) { lo = mid; clo = c; } else hi = mid;
    }

    int base = 0;
#pragma unroll
    for (int e = 0; e < 10; ++e) {
#pragma unroll
        for (int q = 0; q < 4; ++q) {
            const float val = (q == 0) ? v[e].x : (q == 1) ? v[e].y
                            : (q == 2) ? v[e].z : v[e].w;
            const bool take = val > lo;
            const uint64_t m = __ballot(take);
            const int pos = base + __popcll(m & ((1ull << lane) - 1ull));
            if (take && pos < CCAP)
                cidx[(size_t)r * CCAP + pos] = e * 256 + lane * 4 + q;
            base += __popcll(m);
        }
    }
    if (lane == 0) ccnt[r] = (base < CCAP) ? base : CCAP;
}

// ---------------- Exact refine, phase q: candidates with j in [q0, q0+640) -------
// Phasing keeps the W_enc working set at 1.64 MB -> L2-resident gathers.
// Per candidate: 4 fp32 fmaf panel chains (k ascending), shfl-combined
// ((a0+a1)+a2)+a3 + bias -> bit-exact np value into cval[r][slot].
// Block = 4 rows; wave rw handles row r0+rw; lane = (slot16, panel).
__global__ __launch_bounds__(256, 8) void refine_phase(const float* __restrict__ x,
                                                       const float* __restrict__ We,
                                                       const float* __restrict__ be,
                                                       const int* __restrict__ cidx,
                                                       const int* __restrict__ ccnt,
                                                       float* __restrict__ cval,
                                                       int q0) {
    const int tid = threadIdx.x;
    const int rw = tid >> 6, lane = tid & 63;
    const int r = blockIdx.x * 4 + rw;

    __shared__ float xs[4][D_IN];
    for (int i = lane; i < D_IN / 4; i += 64)
        ((float4*)xs[rw])[i] = ((const float4*)(x + (size_t)r * D_IN))[i];
    __syncthreads();

    const int cnt = ccnt[r];
    const int c_sl = lane >> 2, p = lane & 3;
    const int k0 = (p == 0) ? 0  : (p == 1) ? P1 : (p == 2) ? P2 : P3;
    const int k1 = (p == 0) ? P1 : (p == 1) ? P2 : (p == 2) ? P3 : D_IN;
    const int nb = (k1 - k0) >> 4;   // 64B bursts: 12/12/8/8

    for (int pass = 0; pass < 4; ++pass) {
        const int slot = pass * 16 + c_sl;
        int j = -1;
        if (slot < cnt) {
            const int jj = cidx[(size_t)r * CCAP + slot];
            if (jj >= q0 && jj < q0 + 640) j = jj;
        }
        float a = 0.f;
        if (j >= 0) {
            const float4* wp4 = (const float4*)(We + (size_t)j * D_IN + k0);
            const float4* xp4 = (const float4*)&xs[rw][k0];
#pragma unroll 2
            for (int b = 0; b < nb; ++b) {
                const float4 w0 = wp4[b * 4 + 0], w1 = wp4[b * 4 + 1];
                const float4 w2 = wp4[b * 4 + 2], w3 = wp4[b * 4 + 3];
                const float4 x0 = xp4[b * 4 + 0], x1 = xp4[b * 4 + 1];
                const float4 x2 = xp4[b * 4 + 2], x3 = xp4[b * 4 + 3];
                a = fmaf(w0.x, x0.x, a); a = fmaf(w0.y, x0.y, a);
                a = fmaf(w0.z, x0.z, a); a = fmaf(w0.w, x0.w, a);
                a = fmaf(w1.x, x1.x, a); a = fmaf(w1.y, x1.y, a);
                a = fmaf(w1.z, x1.z, a); a = fmaf(w1.w, x1.w, a);
                a = fmaf(w2.x, x2.x, a); a = fmaf(w2.y, x2.y, a);
                a = fmaf(w2.z, x2.z, a); a = fmaf(w2.w, x2.w, a);
                a = fmaf(w3.x, x3.x, a); a = fmaf(w3.y, x3.y, a);
                a = fmaf(w3.z, x3.z, a); a = fmaf(w3.w, x3.w, a);
            }
        }
        // shfl-combine the 4 panel partials of this slot group (exact order)
        const int gb = lane & ~3;
        const float a0 = __shfl(a, gb + 0), a1 = __shfl(a, gb + 1);
        const float a2 = __shfl(a, gb + 2), a3 = __shfl(a, gb + 3);
        if (p == 0 && j >= 0)
            cval[(size_t)r * CCAP + slot] = (((a0 + a1) + a2) + a3) + be[j];
    }
}

// ---------------- Final select: top-32 on exact values, zero+scatter sparse ------
__global__ __launch_bounds__(256) void select32(const int* __restrict__ cidx,
                                                const int* __restrict__ ccnt,
                                                const float* __restrict__ cval,
                                                float* __restrict__ sparse,
                                                float* __restrict__ vals,
                                                int* __restrict__ idxs) {
    const int rw = threadIdx.x >> 6, lane = threadIdx.x & 63;
    const int r = blockIdx.x * 4 + rw;
    const int cnt = ccnt[r];

    const float NEGINF = -__builtin_inff();
    float val = (lane < cnt) ? cval[(size_t)r * CCAP + lane] : NEGINF;
    int   j   = (lane < cnt) ? cidx[(size_t)r * CCAP + lane] : 0x7fffffff;
    float mv = val; int mi = j;
    bool selected = false;
    for (int t = 0; t < K_SEL; ++t) {
        float bv = mv; int bi = mi;
#pragma unroll
        for (int off = 1; off < 64; off <<= 1) {
            float ov = __shfl_xor(bv, off);
            int   oi = __shfl_xor(bi, off);
            if (ov > bv || (ov == bv && oi < bi)) { bv = ov; bi = oi; }
        }
        if (lane == 0) {
            vals[(size_t)r * K_SEL + t] = bv;
            idxs[(size_t)r * K_SEL + t] = bi;
        }
        if (bi == mi) {           // winner lane (candidate indices unique, cnt>=48>32)
            selected = true;
            mv = NEGINF; mi = 0x7fffffff;
        }
    }

    float4 z; z.x = z.y = z.z = z.w = 0.f;
    float4* srow4 = (float4*)(sparse + (size_t)r * D_LAT);
    for (int i = lane; i < D_LAT / 4; i += 64) srow4[i] = z;
    __builtin_amdgcn_s_waitcnt(0);   // vmcnt(0): zero-stores complete before scatter
    if (selected) sparse[(size_t)r * D_LAT + j] = val;
}

// ---------------- Decoder: recon[r] = sum_k vals[r][k] * WdT[idx[r][k]][:] + b_dec
__global__ __launch_bounds__(256) void dec_kernel(const float* __restrict__ vals,
                                                  const int* __restrict__ idxs,
                                                  const float* __restrict__ WdT,
                                                  const float* __restrict__ bdec,
                                                  float* __restrict__ recon) {
    const int wave = threadIdx.x >> 6, lane = threadIdx.x & 63;
    const int r = blockIdx.x * 4 + wave;

    float lv = 0.f; int li = 0;
    if (lane < K_SEL) {
        lv = vals[(size_t)r * K_SEL + lane];
        li = idxs[(size_t)r * K_SEL + lane];
    }
    float acc[10];
#pragma unroll
    for (int e = 0; e < 10; ++e) acc[e] = bdec[lane + e * 64];

#pragma unroll 4
    for (int k = 0; k < K_SEL; ++k) {
        float vkv = __shfl(lv, k);
        int   jj  = __shfl(li, k);
        const float* wr = WdT + (size_t)jj * D_IN + lane;
#pragma unroll
        for (int e = 0; e < 10; ++e) acc[e] = fmaf(vkv, wr[e * 64], acc[e]);
    }
    float* out = recon + (size_t)r * D_IN + lane;
#pragma unroll
    for (int e = 0; e < 10; ++e) out[e * 64] = acc[e];
}

extern "C" void kernel_launch(void* const* d_in, const int* in_sizes, int n_in,
                              void* d_out, int out_size, void* d_ws, size_t ws_size,
                              hipStream_t stream) {
    const float* x     = (const float*)d_in[0];
    const float* W_enc = (const float*)d_in[1];
    const float* b_enc = (const float*)d_in[2];
    const float* W_dec = (const float*)d_in[3];
    const float* b_dec = (const float*)d_in[4];

    float* recon  = (float*)d_out;                                  // [B][640]
    float* sparse = (float*)d_out + (size_t)B_ROWS * D_IN;          // [B][2560]

    // xB (bf16 copy of x, 84MB) parks in the recon region (167MB): recon is only
    // written by dec_kernel, which runs after enc_mfma has consumed xB.
    ushort* xB = (ushort*)recon;

    char* ws = (char*)d_ws;
    size_t off = 0;
    float*  WdT  = (float*) (ws + off); off += (size_t)D_LAT * D_IN * 4;    // 6.55 MB
    ushort* WeB  = (ushort*)(ws + off); off += (size_t)D_LAT * D_IN * 2;    // 3.28 MB
    int*    cidx = (int*)   (ws + off); off += (size_t)B_ROWS * CCAP * 4;   // 16.8 MB
    int*    ccnt = (int*)   (ws + off); off += (size_t)B_ROWS * 4;          // 0.26 MB
    float*  cval = (float*) (ws + off); off += (size_t)B_ROWS * CCAP * 4;   // 16.8 MB
    float*  vals = (float*) (ws + off); off += (size_t)B_ROWS * K_SEL * 4;  // 8.4 MB
    int*    idxs = (int*)   (ws + off);                                     // 8.4 MB

    hipLaunchKernelGGL(cvt_bf16, dim3((size_t)B_ROWS * D_IN / 1024), dim3(256), 0, stream,
                       x, xB);
    hipLaunchKernelGGL(cvt_bf16, dim3((size_t)D_LAT * D_IN / 1024), dim3(256), 0, stream,
                       W_enc, WeB);
    hipLaunchKernelGGL(transpose_wdec, dim3(D_LAT / 32, D_IN / 32), dim3(256), 0, stream,
                       W_dec, WdT);
    hipLaunchKernelGGL(enc_mfma, dim3(D_LAT / 128, B_ROWS / 128), dim3(256), 0, stream,
                       xB, WeB, b_enc, sparse);
    hipLaunchKernelGGL(topk_cand, dim3(B_ROWS / 4), dim3(256), 0, stream,
                       sparse, cidx, ccnt);
    for (int q = 0; q < 4; ++q)
        hipLaunchKernelGGL(refine_phase, dim3(B_ROWS / 4), dim3(256), 0, stream,
                           x, W_enc, b_enc, cidx, ccnt, cval, q * 640);
    hipLaunchKernelGGL(select32, dim3(B_ROWS / 4), dim3(256), 0, stream,
                       cidx, ccnt, cval, sparse, vals, idxs);
    hipLaunchKernelGGL(dec_kernel, dim3(B_ROWS / 4), dim3(256), 0, stream,
                       vals, idxs, WdT, b_dec, recon);
}

// Round 17
// 1638.632 us; speedup vs baseline: 2.7718x; 1.5842x over previous
//
#include <hip/hip_runtime.h>
#include <cstdint>

#define B_ROWS 65536
#define D_IN   640
#define D_LAT  2560
#define K_SEL  32
#define NCAND  48      // minimum candidates (threshold targets count in [48,64])
#define CCAP   64      // candidate capacity per row
#define DELTA  0.03f   // ambiguity half-window vs bf16-GEMM error (sigma~1.6e-3)
// np-exact K-panel boundaries (OpenBLAS SKYLAKEX Q=192): 192+192+128+128
#define P1 192
#define P2 384
#define P3 512

typedef __attribute__((ext_vector_type(8))) short short8;
typedef __attribute__((ext_vector_type(4))) float f32x4;

static __device__ __forceinline__ ushort f2bf(float f) {
    uint32_t u = __float_as_uint(f);
    u += 0x7fffu + ((u >> 16) & 1u);   // round-to-nearest-even
    return (ushort)(u >> 16);
}

// ---------------- generic fp32 -> bf16 convert (4 elems/thread) -------------------
__global__ __launch_bounds__(256) void cvt_bf16(const float* __restrict__ src,
                                                ushort* __restrict__ dst) {
    const size_t i = ((size_t)blockIdx.x * 256 + threadIdx.x) * 4;
    float4 v = *(const float4*)(src + i);
    ushort4 o;
    o.x = f2bf(v.x); o.y = f2bf(v.y); o.z = f2bf(v.z); o.w = f2bf(v.w);
    *(ushort4*)(dst + i) = o;
}

// ---------------- W_dec transpose: [640][2560] -> WdT [2560][640] ----------------
__global__ __launch_bounds__(256) void transpose_wdec(const float* __restrict__ Wd,
                                                      float* __restrict__ WdT) {
    __shared__ float t[32][33];
    const int j0 = blockIdx.x * 32;
    const int i0 = blockIdx.y * 32;
    const int tx = threadIdx.x & 31, ty = threadIdx.x >> 5;
#pragma unroll
    for (int q = 0; q < 4; ++q)
        t[ty + 8 * q][tx] = Wd[(size_t)(i0 + ty + 8 * q) * D_LAT + j0 + tx];
    __syncthreads();
#pragma unroll
    for (int q = 0; q < 4; ++q)
        WdT[(size_t)(j0 + ty + 8 * q) * D_IN + i0 + tx] = t[tx][ty + 8 * q];
}

// ---------------- bf16 MFMA filter GEMM (both operands pre-converted) ------------
__global__ __launch_bounds__(256, 2) void enc_mfma(const ushort* __restrict__ A,
                                                   const ushort* __restrict__ Wb,
                                                   const float* __restrict__ bias,
                                                   float* __restrict__ C) {
    __shared__ ushort Al[128][40];   // pad 32->40 (80B row): 2-way conflicts = free
    __shared__ ushort Bl[128][40];
    const int tid = threadIdx.x;
    const int n0 = blockIdx.x * 128;
    const int m0 = blockIdx.y * 128;
    const int srow = tid >> 1, shalf = tid & 1;
    const ushort* Ap = A  + (size_t)(m0 + srow) * D_IN + shalf * 16;
    const ushort* Bp = Wb + (size_t)(n0 + srow) * D_IN + shalf * 16;

    const int w = tid >> 6, l = tid & 63;
    const int wm = w >> 1, wn = w & 1;
    const int fr = l & 15, ko = l >> 4;

    f32x4 acc[4][4];
#pragma unroll
    for (int i = 0; i < 4; ++i)
#pragma unroll
        for (int j = 0; j < 4; ++j) acc[i][j] = (f32x4)0.0f;

    uint4 a0, a1, b0, b1;
#define LOADT(KT)                                                    \
    {                                                                \
        const uint* ap = (const uint*)(Ap + (KT) * 32);              \
        a0 = *(const uint4*)(ap);                                    \
        a1 = *(const uint4*)(ap + 4);                                \
        const uint* bp = (const uint*)(Bp + (KT) * 32);              \
        b0 = *(const uint4*)(bp);                                    \
        b1 = *(const uint4*)(bp + 4);                                \
    }

    LOADT(0);
    const int NT = D_IN / 32;   // 20
    for (int kt = 0; kt < NT; ++kt) {
        *(uint4*)&Al[srow][shalf * 16]     = a0;
        *(uint4*)&Al[srow][shalf * 16 + 8] = a1;
        *(uint4*)&Bl[srow][shalf * 16]     = b0;
        *(uint4*)&Bl[srow][shalf * 16 + 8] = b1;
        __syncthreads();
        if (kt + 1 < NT) LOADT(kt + 1);

        short8 af[4], bf[4];
#pragma unroll
        for (int fm = 0; fm < 4; ++fm)
            af[fm] = *(const short8*)&Al[wm * 64 + fm * 16 + fr][ko * 8];
#pragma unroll
        for (int fn = 0; fn < 4; ++fn)
            bf[fn] = *(const short8*)&Bl[wn * 64 + fn * 16 + fr][ko * 8];
#pragma unroll
        for (int fm = 0; fm < 4; ++fm)
#pragma unroll
            for (int fn = 0; fn < 4; ++fn)
                acc[fm][fn] = __builtin_amdgcn_mfma_f32_16x16x32_bf16(
                    af[fm], bf[fn], acc[fm][fn], 0, 0, 0);
        __syncthreads();
    }
#undef LOADT

#pragma unroll
    for (int fn = 0; fn < 4; ++fn) {
        const int col = n0 + wn * 64 + fn * 16 + fr;
        const float bb = bias[col];
#pragma unroll
        for (int fm = 0; fm < 4; ++fm) {
#pragma unroll
            for (int j = 0; j < 4; ++j) {
                const int row = m0 + wm * 64 + fm * 16 + ko * 4 + j;
                C[(size_t)row * D_LAT + col] = acc[fm][fn][j] + bb;
            }
        }
    }
}

// ---------------- Candidate select by threshold (wave-per-row) -------------------
// Emits candidate indices AND their approx (bf16-GEMM) latent values.
__global__ __launch_bounds__(256) void topk_cand(const float* __restrict__ lat,
                                                 int* __restrict__ cidx,
                                                 float* __restrict__ cval,
                                                 int* __restrict__ ccnt) {
    const int wv = threadIdx.x >> 6, lane = threadIdx.x & 63;
    const int r = blockIdx.x * 4 + wv;
    const float* row = lat + (size_t)r * D_LAT;

    float4 v[10];
#pragma unroll
    for (int e = 0; e < 10; ++e)
        v[e] = *(const float4*)(row + e * 256 + lane * 4);

    float mx = v[0].x;
#pragma unroll
    for (int e = 0; e < 10; ++e) {
        mx = fmaxf(mx, fmaxf(fmaxf(v[e].x, v[e].y), fmaxf(v[e].z, v[e].w)));
    }
#pragma unroll
    for (int off = 1; off < 64; off <<= 1) mx = fmaxf(mx, __shfl_xor(mx, off));

    auto countGt = [&](float t) -> int {
        int c = 0;
#pragma unroll
        for (int e = 0; e < 10; ++e)
            c += (v[e].x > t) + (v[e].y > t) + (v[e].z > t) + (v[e].w > t);
#pragma unroll
        for (int off = 1; off < 64; off <<= 1) c += __shfl_xor(c, off);
        return c;
    };

    float lo = mx - 2.0f;
    int clo = countGt(lo);
    if (clo < NCAND) { lo = mx - 4.0f; clo = countGt(lo); }
    if (clo < NCAND) { lo = mx - 16.0f; clo = countGt(lo); }   // paranoia tier
    float hi = mx;                                             // count(>mx)=0
    for (int it = 0; it < 28 && clo > CCAP; ++it) {
        const float mid = 0.5f * (lo + hi);
        const int c = countGt(mid);
        if (c >= NCAND) { lo = mid; clo = c; } else hi = mid;
    }

    int base = 0;
#pragma unroll
    for (int e = 0; e < 10; ++e) {
#pragma unroll
        for (int q = 0; q < 4; ++q) {
            const float val = (q == 0) ? v[e].x : (q == 1) ? v[e].y
                            : (q == 2) ? v[e].z : v[e].w;
            const bool take = val > lo;
            const uint64_t m = __ballot(take);
            const int pos = base + __popcll(m & ((1ull << lane) - 1ull));
            if (take && pos < CCAP) {
                cidx[(size_t)r * CCAP + pos] = e * 256 + lane * 4 + q;
                cval[(size_t)r * CCAP + pos] = val;
            }
            base += __popcll(m);
        }
    }
    if (lane == 0) ccnt[r] = (base < CCAP) ? base : CCAP;
}

// ---------------- Boundary-window refine + select (block-per-row) ----------------
// Selection must be np-exact; values need only bf16-GEMM accuracy (thresholds are
// ~(1/16)*max|ref|). wave0 bisects the approx 32nd value v32a; candidates with
// v > v32a+DELTA are surely-in (keep approx value); only |v-v32a|<=DELTA get the
// bit-exact 4-panel fp32 fmaf chain; exact ordering (tie->lower) fills remaining.
__global__ __launch_bounds__(256, 8) void refine_sel(const float* __restrict__ x,
                                                     const float* __restrict__ We,
                                                     const float* __restrict__ be,
                                                     const int* __restrict__ cidx,
                                                     const float* __restrict__ cval,
                                                     const int* __restrict__ ccnt,
                                                     float* __restrict__ sparse,
                                                     float* __restrict__ vals,
                                                     int* __restrict__ idxs) {
    const int tid = threadIdx.x;
    const int r = blockIdx.x;
    const int lane = tid & 63, wv0 = (tid >> 6) == 0;

    __shared__ float xs[D_IN];
    __shared__ float pv[CCAP][4];
    __shared__ int   scj[CCAP];
    __shared__ unsigned long long winm_s;
    __shared__ int   selj[CCAP];
    __shared__ float selv[CCAP];

    const int cnt = ccnt[r];
    for (int i = tid; i < D_IN / 4; i += 256)
        ((float4*)xs)[i] = ((const float4*)(x + (size_t)r * D_IN))[i];

    float v = -__builtin_inff(); int j = 0x7fffffff;
    if (wv0) {
        if (lane < cnt) {
            j = cidx[(size_t)r * CCAP + lane];
            v = cval[(size_t)r * CCAP + lane];
        }
        scj[lane] = j;
        // bisect the approx 32nd value among candidates
        float mxv = v, mnv = (lane < cnt) ? v : __builtin_inff();
#pragma unroll
        for (int off = 1; off < 64; off <<= 1) {
            mxv = fmaxf(mxv, __shfl_xor(mxv, off));
            mnv = fminf(mnv, __shfl_xor(mnv, off));
        }
        auto cgt = [&](float t) -> int {
            int c = (v > t) ? 1 : 0;
#pragma unroll
            for (int off = 1; off < 64; off <<= 1) c += __shfl_xor(c, off);
            return c;
        };
        float blo = mnv - 0.01f, bhi = mxv;
        for (int it = 0; it < 30; ++it) {
            const float mid = 0.5f * (blo + bhi);
            if (cgt(mid) >= K_SEL) blo = mid; else bhi = mid;
        }
        const float v32a = blo;
        const bool sure_in = (lane < cnt) && (v > v32a + DELTA);
        const bool inwin   = (lane < cnt) && !sure_in && (v > v32a - DELTA);
        if (lane == 0) winm_s = 0ull;
        const uint64_t wm = __ballot(inwin);
        if (lane == 0) winm_s = wm;
    }
    __syncthreads();

    // exact chains for window candidates only: thread = (slot, panel)
    {
        const int c = tid >> 2, p = tid & 3;
        if ((winm_s >> c) & 1ull) {
            const int jj = scj[c];
            const int k0 = (p == 0) ? 0  : (p == 1) ? P1 : (p == 2) ? P2 : P3;
            const int k1 = (p == 0) ? P1 : (p == 1) ? P2 : (p == 2) ? P3 : D_IN;
            const float4* wp4 = (const float4*)(We + (size_t)jj * D_IN + k0);
            const float4* xp4 = (const float4*)&xs[k0];
            const int nb = (k1 - k0) >> 4;
            float a = 0.f;
#pragma unroll 2
            for (int b = 0; b < nb; ++b) {
                const float4 w0 = wp4[b * 4 + 0], w1 = wp4[b * 4 + 1];
                const float4 w2 = wp4[b * 4 + 2], w3 = wp4[b * 4 + 3];
                const float4 x0 = xp4[b * 4 + 0], x1 = xp4[b * 4 + 1];
                const float4 x2 = xp4[b * 4 + 2], x3 = xp4[b * 4 + 3];
                a = fmaf(w0.x, x0.x, a); a = fmaf(w0.y, x0.y, a);
                a = fmaf(w0.z, x0.z, a); a = fmaf(w0.w, x0.w, a);
                a = fmaf(w1.x, x1.x, a); a = fmaf(w1.y, x1.y, a);
                a = fmaf(w1.z, x1.z, a); a = fmaf(w1.w, x1.w, a);
                a = fmaf(w2.x, x2.x, a); a = fmaf(w2.y, x2.y, a);
                a = fmaf(w2.z, x2.z, a); a = fmaf(w2.w, x2.w, a);
                a = fmaf(w3.x, x3.x, a); a = fmaf(w3.y, x3.y, a);
                a = fmaf(w3.z, x3.z, a); a = fmaf(w3.w, x3.w, a);
            }
            pv[c][p] = a;
        }
    }
    __syncthreads();

    if (wv0) {
        const float NEGINF = -__builtin_inff();
        // recompute flags (cheap, register-resident v)
        // (v32a must be recomputed identically: redo bisect-free via flags from winm)
        const bool inwin = (winm_s >> lane) & 1ull;
        // sure_in = has v greater than all window members' region: recompute via
        // the same classification: v > v32a+DELTA. Reconstruct v32a from ballot is
        // awkward; instead recompute bisect (identical inputs -> identical result).
        float mxv = v, mnv = (lane < cnt) ? v : __builtin_inff();
#pragma unroll
        for (int off = 1; off < 64; off <<= 1) {
            mxv = fmaxf(mxv, __shfl_xor(mxv, off));
            mnv = fminf(mnv, __shfl_xor(mnv, off));
        }
        auto cgt = [&](float t) -> int {
            int c = (v > t) ? 1 : 0;
#pragma unroll
            for (int off = 1; off < 64; off <<= 1) c += __shfl_xor(c, off);
            return c;
        };
        float blo = mnv - 0.01f, bhi = mxv;
        for (int it = 0; it < 30; ++it) {
            const float mid = 0.5f * (blo + bhi);
            if (cgt(mid) >= K_SEL) blo = mid; else bhi = mid;
        }
        const float v32a = blo;
        const bool sure_in = (lane < cnt) && (v > v32a + DELTA);
        const int n_in = __popcll(__ballot(sure_in));
        const int need = K_SEL - n_in;

        float ev = NEGINF; int ej = 0x7fffffff;
        float exval = 0.f;
        if (inwin) {
            exval = (((pv[lane][0] + pv[lane][1]) + pv[lane][2]) + pv[lane][3]) + be[j];
            ev = exval; ej = j;
        }
        bool selw = false;
        for (int t = 0; t < need; ++t) {
            float bv = ev; int bi = ej;
#pragma unroll
            for (int off = 1; off < 64; off <<= 1) {
                float ov = __shfl_xor(bv, off);
                int   oi = __shfl_xor(bi, off);
                if (ov > bv || (ov == bv && oi < bi)) { bv = ov; bi = oi; }
            }
            if (bi == ej && inwin) {   // winner lane (indices unique)
                selw = true;
                ev = NEGINF; ej = 0x7fffffff;
            }
        }
        const bool selected = sure_in || selw;
        const float outv = sure_in ? v : exval;
        const uint64_t sm = __ballot(selected);
        if (selected) {
            const int pos = __popcll(sm & ((1ull << lane) - 1ull));
            vals[(size_t)r * K_SEL + pos] = outv;
            idxs[(size_t)r * K_SEL + pos] = j;
        }
        selj[lane] = selected ? j : -1;
        selv[lane] = outv;
    }
    __syncthreads();

    float4 z; z.x = z.y = z.z = z.w = 0.f;
    float4* srow4 = (float4*)(sparse + (size_t)r * D_LAT);
    for (int i = tid; i < D_LAT / 4; i += 256) srow4[i] = z;
    __syncthreads();
    if (tid < CCAP) {
        const int jj = selj[tid];
        if (jj >= 0) sparse[(size_t)r * D_LAT + jj] = selv[tid];
    }
}

// ---------------- Decoder: recon[r] = sum_k vals[r][k] * WdT[idx[r][k]][:] + b_dec
__global__ __launch_bounds__(256) void dec_kernel(const float* __restrict__ vals,
                                                  const int* __restrict__ idxs,
                                                  const float* __restrict__ WdT,
                                                  const float* __restrict__ bdec,
                                                  float* __restrict__ recon) {
    const int wave = threadIdx.x >> 6, lane = threadIdx.x & 63;
    const int r = blockIdx.x * 4 + wave;

    float lv = 0.f; int li = 0;
    if (lane < K_SEL) {
        lv = vals[(size_t)r * K_SEL + lane];
        li = idxs[(size_t)r * K_SEL + lane];
    }
    float acc[10];
#pragma unroll
    for (int e = 0; e < 10; ++e) acc[e] = bdec[lane + e * 64];

#pragma unroll 4
    for (int k = 0; k < K_SEL; ++k) {
        float vkv = __shfl(lv, k);
        int   jj  = __shfl(li, k);
        const float* wr = WdT + (size_t)jj * D_IN + lane;
#pragma unroll
        for (int e = 0; e < 10; ++e) acc[e] = fmaf(vkv, wr[e * 64], acc[e]);
    }
    float* out = recon + (size_t)r * D_IN + lane;
#pragma unroll
    for (int e = 0; e < 10; ++e) out[e * 64] = acc[e];
}

extern "C" void kernel_launch(void* const* d_in, const int* in_sizes, int n_in,
                              void* d_out, int out_size, void* d_ws, size_t ws_size,
                              hipStream_t stream) {
    const float* x     = (const float*)d_in[0];
    const float* W_enc = (const float*)d_in[1];
    const float* b_enc = (const float*)d_in[2];
    const float* W_dec = (const float*)d_in[3];
    const float* b_dec = (const float*)d_in[4];

    float* recon  = (float*)d_out;                                  // [B][640]
    float* sparse = (float*)d_out + (size_t)B_ROWS * D_IN;          // [B][2560]

    // xB (bf16 copy of x, 84MB) parks in the recon region (167MB): recon is only
    // written by dec_kernel, which runs after enc_mfma has consumed xB.
    ushort* xB = (ushort*)recon;

    char* ws = (char*)d_ws;
    size_t off = 0;
    float*  WdT  = (float*) (ws + off); off += (size_t)D_LAT * D_IN * 4;    // 6.55 MB
    ushort* WeB  = (ushort*)(ws + off); off += (size_t)D_LAT * D_IN * 2;    // 3.28 MB
    int*    cidx = (int*)   (ws + off); off += (size_t)B_ROWS * CCAP * 4;   // 16.8 MB
    float*  cval = (float*) (ws + off); off += (size_t)B_ROWS * CCAP * 4;   // 16.8 MB
    int*    ccnt = (int*)   (ws + off); off += (size_t)B_ROWS * 4;          // 0.26 MB
    float*  vals = (float*) (ws + off); off += (size_t)B_ROWS * K_SEL * 4;  // 8.4 MB
    int*    idxs = (int*)   (ws + off);                                     // 8.4 MB

    hipLaunchKernelGGL(cvt_bf16, dim3((size_t)B_ROWS * D_IN / 1024), dim3(256), 0, stream,
                       x, xB);
    hipLaunchKernelGGL(cvt_bf16, dim3((size_t)D_LAT * D_IN / 1024), dim3(256), 0, stream,
                       W_enc, WeB);
    hipLaunchKernelGGL(transpose_wdec, dim3(D_LAT / 32, D_IN / 32), dim3(256), 0, stream,
                       W_dec, WdT);
    hipLaunchKernelGGL(enc_mfma, dim3(D_LAT / 128, B_ROWS / 128), dim3(256), 0, stream,
                       xB, WeB, b_enc, sparse);
    hipLaunchKernelGGL(topk_cand, dim3(B_ROWS / 4), dim3(256), 0, stream,
                       sparse, cidx, cval, ccnt);
    hipLaunchKernelGGL(refine_sel, dim3(B_ROWS), dim3(256), 0, stream,
                       x, W_enc, b_enc, cidx, cval, ccnt, sparse, vals, idxs);
    hipLaunchKernelGGL(dec_kernel, dim3(B_ROWS / 4), dim3(256), 0, stream,
                       vals, idxs, WdT, b_dec, recon);
}

// Round 20
// 1424.179 us; speedup vs baseline: 3.1892x; 1.1506x over previous
//
#include <hip/hip_runtime.h>
#include <cstdint>

#define B_ROWS 65536
#define D_IN   640
#define D_LAT  2560
#define K_SEL  32
#define NCAND  48      // minimum candidates (threshold targets count in [48,64])
#define CCAP   64      // candidate capacity per row
#define DELTA  0.03f   // ambiguity half-window vs bf16-GEMM error (sigma~1.6e-3)
// np-exact K-panel boundaries (OpenBLAS SKYLAKEX Q=192): 192+192+128+128
#define P1 192
#define P2 384
#define P3 512

typedef __attribute__((ext_vector_type(8))) short short8;
typedef __attribute__((ext_vector_type(4))) float f32x4;

static __device__ __forceinline__ ushort f2bf(float f) {
    uint32_t u = __float_as_uint(f);
    u += 0x7fffu + ((u >> 16) & 1u);   // round-to-nearest-even
    return (ushort)(u >> 16);
}

// ---------------- generic fp32 -> bf16 convert (4 elems/thread) -------------------
__global__ __launch_bounds__(256) void cvt_bf16(const float* __restrict__ src,
                                                ushort* __restrict__ dst) {
    const size_t i = ((size_t)blockIdx.x * 256 + threadIdx.x) * 4;
    float4 v = *(const float4*)(src + i);
    ushort4 o;
    o.x = f2bf(v.x); o.y = f2bf(v.y); o.z = f2bf(v.z); o.w = f2bf(v.w);
    *(ushort4*)(dst + i) = o;
}

// ---------------- W_dec transpose: [640][2560] -> WdT [2560][640] ----------------
__global__ __launch_bounds__(256) void transpose_wdec(const float* __restrict__ Wd,
                                                      float* __restrict__ WdT) {
    __shared__ float t[32][33];
    const int j0 = blockIdx.x * 32;
    const int i0 = blockIdx.y * 32;
    const int tx = threadIdx.x & 31, ty = threadIdx.x >> 5;
#pragma unroll
    for (int q = 0; q < 4; ++q)
        t[ty + 8 * q][tx] = Wd[(size_t)(i0 + ty + 8 * q) * D_LAT + j0 + tx];
    __syncthreads();
#pragma unroll
    for (int q = 0; q < 4; ++q)
        WdT[(size_t)(j0 + ty + 8 * q) * D_IN + i0 + tx] = t[tx][ty + 8 * q];
}

// ---------------- bf16 MFMA filter GEMM (both operands pre-converted) ------------
__global__ __launch_bounds__(256, 3) void enc_mfma(const ushort* __restrict__ A,
                                                   const ushort* __restrict__ Wb,
                                                   const float* __restrict__ bias,
                                                   float* __restrict__ C) {
    __shared__ ushort Al[128][40];   // pad 32->40 (80B row): 2-way conflicts = free
    __shared__ ushort Bl[128][40];
    const int tid = threadIdx.x;
    const int n0 = blockIdx.x * 128;
    const int m0 = blockIdx.y * 128;
    const int srow = tid >> 1, shalf = tid & 1;
    const ushort* Ap = A  + (size_t)(m0 + srow) * D_IN + shalf * 16;
    const ushort* Bp = Wb + (size_t)(n0 + srow) * D_IN + shalf * 16;

    const int w = tid >> 6, l = tid & 63;
    const int wm = w >> 1, wn = w & 1;
    const int fr = l & 15, ko = l >> 4;

    f32x4 acc[4][4];
#pragma unroll
    for (int i = 0; i < 4; ++i)
#pragma unroll
        for (int j = 0; j < 4; ++j) acc[i][j] = (f32x4)0.0f;

    uint4 a0, a1, b0, b1;
#define LOADT(KT)                                                    \
    {                                                                \
        const uint* ap = (const uint*)(Ap + (KT) * 32);              \
        a0 = *(const uint4*)(ap);                                    \
        a1 = *(const uint4*)(ap + 4);                                \
        const uint* bp = (const uint*)(Bp + (KT) * 32);              \
        b0 = *(const uint4*)(bp);                                    \
        b1 = *(const uint4*)(bp + 4);                                \
    }

    LOADT(0);
    const int NT = D_IN / 32;   // 20
    for (int kt = 0; kt < NT; ++kt) {
        *(uint4*)&Al[srow][shalf * 16]     = a0;
        *(uint4*)&Al[srow][shalf * 16 + 8] = a1;
        *(uint4*)&Bl[srow][shalf * 16]     = b0;
        *(uint4*)&Bl[srow][shalf * 16 + 8] = b1;
        __syncthreads();
        if (kt + 1 < NT) LOADT(kt + 1);

        short8 af[4], bf[4];
#pragma unroll
        for (int fm = 0; fm < 4; ++fm)
            af[fm] = *(const short8*)&Al[wm * 64 + fm * 16 + fr][ko * 8];
#pragma unroll
        for (int fn = 0; fn < 4; ++fn)
            bf[fn] = *(const short8*)&Bl[wn * 64 + fn * 16 + fr][ko * 8];
#pragma unroll
        for (int fm = 0; fm < 4; ++fm)
#pragma unroll
            for (int fn = 0; fn < 4; ++fn)
                acc[fm][fn] = __builtin_amdgcn_mfma_f32_16x16x32_bf16(
                    af[fm], bf[fn], acc[fm][fn], 0, 0, 0);
        __syncthreads();
    }
#undef LOADT

#pragma unroll
    for (int fn = 0; fn < 4; ++fn) {
        const int col = n0 + wn * 64 + fn * 16 + fr;
        const float bb = bias[col];
#pragma unroll
        for (int fm = 0; fm < 4; ++fm) {
#pragma unroll
            for (int j = 0; j < 4; ++j) {
                const int row = m0 + wm * 64 + fm * 16 + ko * 4 + j;
                C[(size_t)row * D_LAT + col] = acc[fm][fn][j] + bb;
            }
        }
    }
}

// ---------------- Candidate select by threshold (wave-per-row) -------------------
// Emits candidate indices AND their approx (bf16-GEMM) latent values.
__global__ __launch_bounds__(256) void topk_cand(const float* __restrict__ lat,
                                                 int* __restrict__ cidx,
                                                 float* __restrict__ cval,
                                                 int* __restrict__ ccnt) {
    const int wv = threadIdx.x >> 6, lane = threadIdx.x & 63;
    const int r = blockIdx.x * 4 + wv;
    const float* row = lat + (size_t)r * D_LAT;

    float4 v[10];
#pragma unroll
    for (int e = 0; e < 10; ++e)
        v[e] = *(const float4*)(row + e * 256 + lane * 4);

    float mx = v[0].x;
#pragma unroll
    for (int e = 0; e < 10; ++e) {
        mx = fmaxf(mx, fmaxf(fmaxf(v[e].x, v[e].y), fmaxf(v[e].z, v[e].w)));
    }
#pragma unroll
    for (int off = 1; off < 64; off <<= 1) mx = fmaxf(mx, __shfl_xor(mx, off));

    auto countGt = [&](float t) -> int {
        int c = 0;
#pragma unroll
        for (int e = 0; e < 10; ++e)
            c += (v[e].x > t) + (v[e].y > t) + (v[e].z > t) + (v[e].w > t);
#pragma unroll
        for (int off = 1; off < 64; off <<= 1) c += __shfl_xor(c, off);
        return c;
    };

    float lo = mx - 2.0f;
    int clo = countGt(lo);
    if (clo < NCAND) { lo = mx - 4.0f; clo = countGt(lo); }
    if (clo < NCAND) { lo = mx - 16.0f; clo = countGt(lo); }   // paranoia tier
    float hi = mx;                                             // count(>mx)=0
    for (int it = 0; it < 28 && clo > CCAP; ++it) {
        const float mid = 0.5f * (lo + hi);
        const int c = countGt(mid);
        if (c >= NCAND) { lo = mid; clo = c; } else hi = mid;
    }

    int base = 0;
#pragma unroll
    for (int e = 0; e < 10; ++e) {
#pragma unroll
        for (int q = 0; q < 4; ++q) {
            const float val = (q == 0) ? v[e].x : (q == 1) ? v[e].y
                            : (q == 2) ? v[e].z : v[e].w;
            const bool take = val > lo;
            const uint64_t m = __ballot(take);
            const int pos = base + __popcll(m & ((1ull << lane) - 1ull));
            if (take && pos < CCAP) {
                cidx[(size_t)r * CCAP + pos] = e * 256 + lane * 4 + q;
                cval[(size_t)r * CCAP + pos] = val;
            }
            base += __popcll(m);
        }
    }
    if (lane == 0) ccnt[r] = (base < CCAP) ? base : CCAP;
}

// ---------------- Boundary-window refine + select (block-per-row) ----------------
// Same logic as the R17 passing kernel; single bisect (flags carried in regs).
__global__ __launch_bounds__(256, 8) void refine_sel(const float* __restrict__ x,
                                                     const float* __restrict__ We,
                                                     const float* __restrict__ be,
                                                     const int* __restrict__ cidx,
                                                     const float* __restrict__ cval,
                                                     const int* __restrict__ ccnt,
                                                     float* __restrict__ sparse,
                                                     float* __restrict__ vals,
                                                     int* __restrict__ idxs) {
    const int tid = threadIdx.x;
    const int r = blockIdx.x;
    const int lane = tid & 63;
    const bool wv0 = (tid >> 6) == 0;

    __shared__ float xs[D_IN];
    __shared__ float pv[CCAP][4];
    __shared__ int   scj[CCAP];
    __shared__ unsigned long long winm_s;
    __shared__ int   selj[CCAP];
    __shared__ float selv[CCAP];

    const int cnt = ccnt[r];
    for (int i = tid; i < D_IN / 4; i += 256)
        ((float4*)xs)[i] = ((const float4*)(x + (size_t)r * D_IN))[i];

    // classification state computed once in wave0, carried in registers
    float v = -__builtin_inff(); int j = 0x7fffffff;
    bool sure_in = false, inwin = false;
    int n_in = 0;
    if (wv0) {
        if (lane < cnt) {
            j = cidx[(size_t)r * CCAP + lane];
            v = cval[(size_t)r * CCAP + lane];
        }
        scj[lane] = j;
        // bisect the approx 32nd value among candidates
        float mxv = v, mnv = (lane < cnt) ? v : __builtin_inff();
#pragma unroll
        for (int off = 1; off < 64; off <<= 1) {
            mxv = fmaxf(mxv, __shfl_xor(mxv, off));
            mnv = fminf(mnv, __shfl_xor(mnv, off));
        }
        auto cgt = [&](float t) -> int {
            int c = (v > t) ? 1 : 0;
#pragma unroll
            for (int off = 1; off < 64; off <<= 1) c += __shfl_xor(c, off);
            return c;
        };
        float blo = mnv - 0.01f, bhi = mxv;
        for (int it = 0; it < 20; ++it) {
            const float mid = 0.5f * (blo + bhi);
            if (cgt(mid) >= K_SEL) blo = mid; else bhi = mid;
        }
        const float v32a = blo;
        sure_in = (lane < cnt) && (v > v32a + DELTA);
        inwin   = (lane < cnt) && !sure_in && (v > v32a - DELTA);
        n_in = __popcll(__ballot(sure_in));
        const uint64_t wm = __ballot(inwin);
        if (lane == 0) winm_s = wm;
    }
    __syncthreads();

    // exact chains for window candidates only: thread = (slot, panel)
    {
        const int c = tid >> 2, p = tid & 3;
        if ((winm_s >> c) & 1ull) {
            const int jj = scj[c];
            const int k0 = (p == 0) ? 0  : (p == 1) ? P1 : (p == 2) ? P2 : P3;
            const int k1 = (p == 0) ? P1 : (p == 1) ? P2 : (p == 2) ? P3 : D_IN;
            const float4* wp4 = (const float4*)(We + (size_t)jj * D_IN + k0);
            const float4* xp4 = (const float4*)&xs[k0];
            const int nb = (k1 - k0) >> 4;
            float a = 0.f;
#pragma unroll 2
            for (int b = 0; b < nb; ++b) {
                const float4 w0 = wp4[b * 4 + 0], w1 = wp4[b * 4 + 1];
                const float4 w2 = wp4[b * 4 + 2], w3 = wp4[b * 4 + 3];
                const float4 x0 = xp4[b * 4 + 0], x1 = xp4[b * 4 + 1];
                const float4 x2 = xp4[b * 4 + 2], x3 = xp4[b * 4 + 3];
                a = fmaf(w0.x, x0.x, a); a = fmaf(w0.y, x0.y, a);
                a = fmaf(w0.z, x0.z, a); a = fmaf(w0.w, x0.w, a);
                a = fmaf(w1.x, x1.x, a); a = fmaf(w1.y, x1.y, a);
                a = fmaf(w1.z, x1.z, a); a = fmaf(w1.w, x1.w, a);
                a = fmaf(w2.x, x2.x, a); a = fmaf(w2.y, x2.y, a);
                a = fmaf(w2.z, x2.z, a); a = fmaf(w2.w, x2.w, a);
                a = fmaf(w3.x, x3.x, a); a = fmaf(w3.y, x3.y, a);
                a = fmaf(w3.z, x3.z, a); a = fmaf(w3.w, x3.w, a);
            }
            pv[c][p] = a;
        }
    }
    __syncthreads();

    if (wv0) {
        const float NEGINF = -__builtin_inff();
        const int need = K_SEL - n_in;

        float ev = NEGINF; int ej = 0x7fffffff;
        float exval = 0.f;
        if (inwin) {
            exval = (((pv[lane][0] + pv[lane][1]) + pv[lane][2]) + pv[lane][3]) + be[j];
            ev = exval; ej = j;
        }
        bool selw = false;
        for (int t = 0; t < need; ++t) {
            float bv = ev; int bi = ej;
#pragma unroll
            for (int off = 1; off < 64; off <<= 1) {
                float ov = __shfl_xor(bv, off);
                int   oi = __shfl_xor(bi, off);
                if (ov > bv || (ov == bv && oi < bi)) { bv = ov; bi = oi; }
            }
            if (bi == ej && inwin) {   // winner lane (indices unique)
                selw = true;
                ev = NEGINF; ej = 0x7fffffff;
            }
        }
        const bool selected = sure_in || selw;
        const float outv = sure_in ? v : exval;
        const uint64_t sm = __ballot(selected);
        if (selected) {
            const int pos = __popcll(sm & ((1ull << lane) - 1ull));
            vals[(size_t)r * K_SEL + pos] = outv;
            idxs[(size_t)r * K_SEL + pos] = j;
        }
        selj[lane] = selected ? j : -1;
        selv[lane] = outv;
    }
    __syncthreads();

    float4 z; z.x = z.y = z.z = z.w = 0.f;
    float4* srow4 = (float4*)(sparse + (size_t)r * D_LAT);
    for (int i = tid; i < D_LAT / 4; i += 256) srow4[i] = z;
    __syncthreads();
    if (tid < CCAP) {
        const int jj = selj[tid];
        if (jj >= 0) sparse[(size_t)r * D_LAT + jj] = selv[tid];
    }
}

// ---------------- Decoder: recon[r] = sum_k vals[r][k] * WdT[idx[r][k]][:] + b_dec
__global__ __launch_bounds__(256) void dec_kernel(const float* __restrict__ vals,
                                                  const int* __restrict__ idxs,
                                                  const float* __restrict__ WdT,
                                                  const float* __restrict__ bdec,
                                                  float* __restrict__ recon) {
    const int wave = threadIdx.x >> 6, lane = threadIdx.x & 63;
    const int r = blockIdx.x * 4 + wave;

    float lv = 0.f; int li = 0;
    if (lane < K_SEL) {
        lv = vals[(size_t)r * K_SEL + lane];
        li = idxs[(size_t)r * K_SEL + lane];
    }
    float acc[10];
#pragma unroll
    for (int e = 0; e < 10; ++e) acc[e] = bdec[lane + e * 64];

#pragma unroll 4
    for (int k = 0; k < K_SEL; ++k) {
        float vkv = __shfl(lv, k);
        int   jj  = __shfl(li, k);
        const float* wr = WdT + (size_t)jj * D_IN + lane;
#pragma unroll
        for (int e = 0; e < 10; ++e) acc[e] = fmaf(vkv, wr[e * 64], acc[e]);
    }
    float* out = recon + (size_t)r * D_IN + lane;
#pragma unroll
    for (int e = 0; e < 10; ++e) out[e * 64] = acc[e];
}

extern "C" void kernel_launch(void* const* d_in, const int* in_sizes, int n_in,
                              void* d_out, int out_size, void* d_ws, size_t ws_size,
                              hipStream_t stream) {
    const float* x     = (const float*)d_in[0];
    const float* W_enc = (const float*)d_in[1];
    const float* b_enc = (const float*)d_in[2];
    const float* W_dec = (const float*)d_in[3];
    const float* b_dec = (const float*)d_in[4];

    float* recon  = (float*)d_out;                                  // [B][640]
    float* sparse = (float*)d_out + (size_t)B_ROWS * D_IN;          // [B][2560]

    // xB (bf16 copy of x, 84MB) parks in the recon region (167MB): recon is only
    // written by dec_kernel, which runs after enc_mfma has consumed xB.
    ushort* xB = (ushort*)recon;

    char* ws = (char*)d_ws;
    size_t off = 0;
    float*  WdT  = (float*) (ws + off); off += (size_t)D_LAT * D_IN * 4;    // 6.55 MB
    ushort* WeB  = (ushort*)(ws + off); off += (size_t)D_LAT * D_IN * 2;    // 3.28 MB
    int*    cidx = (int*)   (ws + off); off += (size_t)B_ROWS * CCAP * 4;   // 16.8 MB
    float*  cval = (float*) (ws + off); off += (size_t)B_ROWS * CCAP * 4;   // 16.8 MB
    int*    ccnt = (int*)   (ws + off); off += (size_t)B_ROWS * 4;          // 0.26 MB
    float*  vals = (float*) (ws + off); off += (size_t)B_ROWS * K_SEL * 4;  // 8.4 MB
    int*    idxs = (int*)   (ws + off);                                     // 8.4 MB

    hipLaunchKernelGGL(cvt_bf16, dim3((size_t)B_ROWS * D_IN / 1024), dim3(256), 0, stream,
                       x, xB);
    hipLaunchKernelGGL(cvt_bf16, dim3((size_t)D_LAT * D_IN / 1024), dim3(256), 0, stream,
                       W_enc, WeB);
    hipLaunchKernelGGL(transpose_wdec, dim3(D_LAT / 32, D_IN / 32), dim3(256), 0, stream,
                       W_dec, WdT);
    hipLaunchKernelGGL(enc_mfma, dim3(D_LAT / 128, B_ROWS / 128), dim3(256), 0, stream,
                       xB, WeB, b_enc, sparse);
    hipLaunchKernelGGL(topk_cand, dim3(B_ROWS / 4), dim3(256), 0, stream,
                       sparse, cidx, cval, ccnt);
    hipLaunchKernelGGL(refine_sel, dim3(B_ROWS), dim3(256), 0, stream,
                       x, W_enc, b_enc, cidx, cval, ccnt, sparse, vals, idxs);
    hipLaunchKernelGGL(dec_kernel, dim3(B_ROWS / 4), dim3(256), 0, stream,
                       vals, idxs, WdT, b_dec, recon);
}

// Round 21
// 1334.978 us; speedup vs baseline: 3.4023x; 1.0668x over previous
//
#include <hip/hip_runtime.h>
#include <cstdint>

#define B_ROWS 65536
#define D_IN   640
#define D_LAT  2560
#define K_SEL  32
#define NCAND  48      // minimum candidates (threshold targets count in [48,64])
#define CCAP   64      // candidate capacity per row
#define DELTA  0.03f   // ambiguity half-window vs bf16-GEMM error (sigma~1.6e-3)
// np-exact K-panel boundaries (OpenBLAS SKYLAKEX Q=192): 192+192+128+128
#define P1 192
#define P2 384
#define P3 512

typedef __attribute__((ext_vector_type(8))) short short8;
typedef __attribute__((ext_vector_type(4))) float f32x4;

static __device__ __forceinline__ ushort f2bf(float f) {
    uint32_t u = __float_as_uint(f);
    u += 0x7fffu + ((u >> 16) & 1u);   // round-to-nearest-even
    return (ushort)(u >> 16);
}

// ---------------- generic fp32 -> bf16 convert (4 elems/thread) -------------------
__global__ __launch_bounds__(256) void cvt_bf16(const float* __restrict__ src,
                                                ushort* __restrict__ dst) {
    const size_t i = ((size_t)blockIdx.x * 256 + threadIdx.x) * 4;
    float4 v = *(const float4*)(src + i);
    ushort4 o;
    o.x = f2bf(v.x); o.y = f2bf(v.y); o.z = f2bf(v.z); o.w = f2bf(v.w);
    *(ushort4*)(dst + i) = o;
}

// ---------------- W_dec transpose: [640][2560] -> WdT [2560][640] ----------------
__global__ __launch_bounds__(256) void transpose_wdec(const float* __restrict__ Wd,
                                                      float* __restrict__ WdT) {
    __shared__ float t[32][33];
    const int j0 = blockIdx.x * 32;
    const int i0 = blockIdx.y * 32;
    const int tx = threadIdx.x & 31, ty = threadIdx.x >> 5;
#pragma unroll
    for (int q = 0; q < 4; ++q)
        t[ty + 8 * q][tx] = Wd[(size_t)(i0 + ty + 8 * q) * D_LAT + j0 + tx];
    __syncthreads();
#pragma unroll
    for (int q = 0; q < 4; ++q)
        WdT[(size_t)(j0 + ty + 8 * q) * D_IN + i0 + tx] = t[tx][ty + 8 * q];
}

// ---------------- bf16 MFMA filter GEMM (both operands pre-converted) ------------
__global__ __launch_bounds__(256, 3) void enc_mfma(const ushort* __restrict__ A,
                                                   const ushort* __restrict__ Wb,
                                                   const float* __restrict__ bias,
                                                   float* __restrict__ C) {
    __shared__ ushort Al[128][40];   // pad 32->40 (80B row): 2-way conflicts = free
    __shared__ ushort Bl[128][40];
    const int tid = threadIdx.x;
    const int n0 = blockIdx.x * 128;
    const int m0 = blockIdx.y * 128;
    const int srow = tid >> 1, shalf = tid & 1;
    const ushort* Ap = A  + (size_t)(m0 + srow) * D_IN + shalf * 16;
    const ushort* Bp = Wb + (size_t)(n0 + srow) * D_IN + shalf * 16;

    const int w = tid >> 6, l = tid & 63;
    const int wm = w >> 1, wn = w & 1;
    const int fr = l & 15, ko = l >> 4;

    f32x4 acc[4][4];
#pragma unroll
    for (int i = 0; i < 4; ++i)
#pragma unroll
        for (int j = 0; j < 4; ++j) acc[i][j] = (f32x4)0.0f;

    uint4 a0, a1, b0, b1;
#define LOADT(KT)                                                    \
    {                                                                \
        const uint* ap = (const uint*)(Ap + (KT) * 32);              \
        a0 = *(const uint4*)(ap);                                    \
        a1 = *(const uint4*)(ap + 4);                                \
        const uint* bp = (const uint*)(Bp + (KT) * 32);              \
        b0 = *(const uint4*)(bp);                                    \
        b1 = *(const uint4*)(bp + 4);                                \
    }

    LOADT(0);
    const int NT = D_IN / 32;   // 20
    for (int kt = 0; kt < NT; ++kt) {
        *(uint4*)&Al[srow][shalf * 16]     = a0;
        *(uint4*)&Al[srow][shalf * 16 + 8] = a1;
        *(uint4*)&Bl[srow][shalf * 16]     = b0;
        *(uint4*)&Bl[srow][shalf * 16 + 8] = b1;
        __syncthreads();
        if (kt + 1 < NT) LOADT(kt + 1);

        short8 af[4], bf[4];
#pragma unroll
        for (int fm = 0; fm < 4; ++fm)
            af[fm] = *(const short8*)&Al[wm * 64 + fm * 16 + fr][ko * 8];
#pragma unroll
        for (int fn = 0; fn < 4; ++fn)
            bf[fn] = *(const short8*)&Bl[wn * 64 + fn * 16 + fr][ko * 8];
#pragma unroll
        for (int fm = 0; fm < 4; ++fm)
#pragma unroll
            for (int fn = 0; fn < 4; ++fn)
                acc[fm][fn] = __builtin_amdgcn_mfma_f32_16x16x32_bf16(
                    af[fm], bf[fn], acc[fm][fn], 0, 0, 0);
        __syncthreads();
    }
#undef LOADT

#pragma unroll
    for (int fn = 0; fn < 4; ++fn) {
        const int col = n0 + wn * 64 + fn * 16 + fr;
        const float bb = bias[col];
#pragma unroll
        for (int fm = 0; fm < 4; ++fm) {
#pragma unroll
            for (int j = 0; j < 4; ++j) {
                const int row = m0 + wm * 64 + fm * 16 + ko * 4 + j;
                C[(size_t)row * D_LAT + col] = acc[fm][fn][j] + bb;
            }
        }
    }
}

// ---------------- Candidate select by threshold (wave-per-row) -------------------
// Emits candidate indices AND their approx (bf16-GEMM) latent values.
__global__ __launch_bounds__(256) void topk_cand(const float* __restrict__ lat,
                                                 int* __restrict__ cidx,
                                                 float* __restrict__ cval,
                                                 int* __restrict__ ccnt) {
    const int wv = threadIdx.x >> 6, lane = threadIdx.x & 63;
    const int r = blockIdx.x * 4 + wv;
    const float* row = lat + (size_t)r * D_LAT;

    float4 v[10];
#pragma unroll
    for (int e = 0; e < 10; ++e)
        v[e] = *(const float4*)(row + e * 256 + lane * 4);

    float mx = v[0].x;
#pragma unroll
    for (int e = 0; e < 10; ++e) {
        mx = fmaxf(mx, fmaxf(fmaxf(v[e].x, v[e].y), fmaxf(v[e].z, v[e].w)));
    }
#pragma unroll
    for (int off = 1; off < 64; off <<= 1) mx = fmaxf(mx, __shfl_xor(mx, off));

    auto countGt = [&](float t) -> int {
        int c = 0;
#pragma unroll
        for (int e = 0; e < 10; ++e)
            c += (v[e].x > t) + (v[e].y > t) + (v[e].z > t) + (v[e].w > t);
#pragma unroll
        for (int off = 1; off < 64; off <<= 1) c += __shfl_xor(c, off);
        return c;
    };

    float lo = mx - 2.0f;
    int clo = countGt(lo);
    if (clo < NCAND) { lo = mx - 4.0f; clo = countGt(lo); }
    if (clo < NCAND) { lo = mx - 16.0f; clo = countGt(lo); }   // paranoia tier
    float hi = mx;                                             // count(>mx)=0
    for (int it = 0; it < 28 && clo > CCAP; ++it) {
        const float mid = 0.5f * (lo + hi);
        const int c = countGt(mid);
        if (c >= NCAND) { lo = mid; clo = c; } else hi = mid;
    }

    int base = 0;
#pragma unroll
    for (int e = 0; e < 10; ++e) {
#pragma unroll
        for (int q = 0; q < 4; ++q) {
            const float val = (q == 0) ? v[e].x : (q == 1) ? v[e].y
                            : (q == 2) ? v[e].z : v[e].w;
            const bool take = val > lo;
            const uint64_t m = __ballot(take);
            const int pos = base + __popcll(m & ((1ull << lane) - 1ull));
            if (take && pos < CCAP) {
                cidx[(size_t)r * CCAP + pos] = e * 256 + lane * 4 + q;
                cval[(size_t)r * CCAP + pos] = val;
            }
            base += __popcll(m);
        }
    }
    if (lane == 0) ccnt[r] = (base < CCAP) ? base : CCAP;
}

// ---------------- Boundary-window refine + select (wave-per-row) -----------------
// Same math as R20's passing kernel, one wave per row (4 rows/block), barriers
// between every LDS produce->consume phase. Writes ONLY vals/idxs (sparse is
// zeroed+scattered by dec_kernel). xs panels padded to banks 0/4/8/12.
__global__ __launch_bounds__(256, 4) void refine_sel(const float* __restrict__ x,
                                                     const float* __restrict__ We,
                                                     const float* __restrict__ be,
                                                     const int* __restrict__ cidx,
                                                     const float* __restrict__ cval,
                                                     const int* __restrict__ ccnt,
                                                     float* __restrict__ vals,
                                                     int* __restrict__ idxs) {
    const int wv = threadIdx.x >> 6, lane = threadIdx.x & 63;
    const int r = blockIdx.x * 4 + wv;

    __shared__ float xs[4][656];     // panel bases 0,196,392,524 (banks 0,4,8,12)
    __shared__ int   winj[4][CCAP];
    __shared__ float exv[4][CCAP];

    const int cnt = ccnt[r];

    // defensive pre-zero of this row's output slots (underfill -> inert 0s)
    if (lane < K_SEL) {
        vals[(size_t)r * K_SEL + lane] = 0.f;
        idxs[(size_t)r * K_SEL + lane] = 0;
    }

    for (int i = lane; i < D_IN; i += 64) {
        const int p  = (i >= P3) ? 3 : (i >= P2) ? 2 : (i >= P1) ? 1 : 0;
        const int kb = (p == 0) ? 0 : (p == 1) ? P1  : (p == 2) ? P2  : P3;
        const int pb = (p == 0) ? 0 : (p == 1) ? 196 : (p == 2) ? 392 : 524;
        xs[wv][pb + i - kb] = x[(size_t)r * D_IN + i];
    }

    float v = -__builtin_inff(); int j = 0x7fffffff;
    if (lane < cnt) {
        j = cidx[(size_t)r * CCAP + lane];
        v = cval[(size_t)r * CCAP + lane];
    }

    float mxv = v, mnv = (lane < cnt) ? v : __builtin_inff();
#pragma unroll
    for (int off = 1; off < 64; off <<= 1) {
        mxv = fmaxf(mxv, __shfl_xor(mxv, off));
        mnv = fminf(mnv, __shfl_xor(mnv, off));
    }
    auto cgt = [&](float t) -> int {
        int c = (v > t) ? 1 : 0;
#pragma unroll
        for (int off = 1; off < 64; off <<= 1) c += __shfl_xor(c, off);
        return c;
    };
    float blo = mnv - 0.01f, bhi = mxv;
    for (int it = 0; it < 20; ++it) {
        const float mid = 0.5f * (blo + bhi);
        if (cgt(mid) >= K_SEL) blo = mid; else bhi = mid;
    }
    const float v32a = blo;
    const bool sure_in = (lane < cnt) && (v > v32a + DELTA);
    const bool inwin   = (lane < cnt) && !sure_in && (v > v32a - DELTA);
    const int n_in = __popcll(__ballot(sure_in));
    const uint64_t wm = __ballot(inwin);
    const int wcnt = __popcll(wm);
    if (inwin) winj[wv][__popcll(wm & ((1ull << lane) - 1ull))] = j;

    __syncthreads();

    // bit-exact 4-panel chains for window members (16 per pass, lane=(rank,panel))
    for (int p0 = 0; p0 < wcnt; p0 += 16) {
        const int rank = p0 + (lane >> 2), pnl = lane & 3;
        float a = 0.f; int jj = 0;
        if (rank < wcnt) {
            jj = winj[wv][rank];
            const int k0 = (pnl == 0) ? 0 : (pnl == 1) ? P1  : (pnl == 2) ? P2  : P3;
            const int k1 = (pnl == 0) ? P1 : (pnl == 1) ? P2 : (pnl == 2) ? P3 : D_IN;
            const int pb = (pnl == 0) ? 0 : (pnl == 1) ? 196 : (pnl == 2) ? 392 : 524;
            const float4* wp4 = (const float4*)(We + (size_t)jj * D_IN + k0);
            const float4* xp4 = (const float4*)&xs[wv][pb];
            const int nb = (k1 - k0) >> 4;   // 64B bursts: 12/12/8/8
#pragma unroll 2
            for (int b = 0; b < nb; ++b) {
                const float4 w0 = wp4[b * 4 + 0], w1 = wp4[b * 4 + 1];
                const float4 w2 = wp4[b * 4 + 2], w3 = wp4[b * 4 + 3];
                const float4 x0 = xp4[b * 4 + 0], x1 = xp4[b * 4 + 1];
                const float4 x2 = xp4[b * 4 + 2], x3 = xp4[b * 4 + 3];
                a = fmaf(w0.x, x0.x, a); a = fmaf(w0.y, x0.y, a);
                a = fmaf(w0.z, x0.z, a); a = fmaf(w0.w, x0.w, a);
                a = fmaf(w1.x, x1.x, a); a = fmaf(w1.y, x1.y, a);
                a = fmaf(w1.z, x1.z, a); a = fmaf(w1.w, x1.w, a);
                a = fmaf(w2.x, x2.x, a); a = fmaf(w2.y, x2.y, a);
                a = fmaf(w2.z, x2.z, a); a = fmaf(w2.w, x2.w, a);
                a = fmaf(w3.x, x3.x, a); a = fmaf(w3.y, x3.y, a);
                a = fmaf(w3.z, x3.z, a); a = fmaf(w3.w, x3.w, a);
            }
        }
        const int gb = lane & ~3;
        const float a0 = __shfl(a, gb + 0), a1 = __shfl(a, gb + 1);
        const float a2 = __shfl(a, gb + 2), a3 = __shfl(a, gb + 3);
        if (pnl == 0 && rank < wcnt)
            exv[wv][rank] = (((a0 + a1) + a2) + a3) + be[jj];
    }
    __syncthreads();

    // emit sure-ins (approx values; order within row irrelevant for dec/scatter)
    const uint64_t sm = __ballot(sure_in);
    if (sure_in) {
        const int pos = __popcll(sm & ((1ull << lane) - 1ull));
        vals[(size_t)r * K_SEL + pos] = v;
        idxs[(size_t)r * K_SEL + pos] = j;
    }

    // pick (32 - n_in) window winners by (exact desc, index asc) = np semantics
    float ev = (lane < wcnt) ? exv[wv][lane] : -__builtin_inff();
    int   ej = (lane < wcnt) ? winj[wv][lane] : 0x7fffffff;
    int need = K_SEL - n_in;
    if (need > wcnt) need = wcnt;    // defensive
    for (int t = 0; t < need; ++t) {
        float bv = ev; int bi = ej;
#pragma unroll
        for (int off = 1; off < 64; off <<= 1) {
            float ov = __shfl_xor(bv, off);
            int   oi = __shfl_xor(bi, off);
            if (ov > bv || (ov == bv && oi < bi)) { bv = ov; bi = oi; }
        }
        if (ej == bi && ej != 0x7fffffff) {   // unique winner lane
            vals[(size_t)r * K_SEL + n_in + t] = ev;
            idxs[(size_t)r * K_SEL + n_in + t] = ej;
            ev = -__builtin_inff(); ej = 0x7fffffff;
        }
    }
}

// ---------------- Decoder + sparse writeback -------------------------------------
// recon[r] = sum_k vals[r][k] * WdT[idx[r][k]][:] + b_dec ; also zeroes the
// sparse row and scatters the 32 selected values (R16-proven pattern).
__global__ __launch_bounds__(256) void dec_kernel(const float* __restrict__ vals,
                                                  const int* __restrict__ idxs,
                                                  const float* __restrict__ WdT,
                                                  const float* __restrict__ bdec,
                                                  float* __restrict__ recon,
                                                  float* __restrict__ sparse) {
    const int wave = threadIdx.x >> 6, lane = threadIdx.x & 63;
    const int r = blockIdx.x * 4 + wave;

    float lv = 0.f; int li = 0;
    if (lane < K_SEL) {
        lv = vals[(size_t)r * K_SEL + lane];
        li = idxs[(size_t)r * K_SEL + lane];
        li = (li < 0) ? 0 : ((li >= D_LAT) ? D_LAT - 1 : li);   // defensive clamp
    }
    float acc[10];
#pragma unroll
    for (int e = 0; e < 10; ++e) acc[e] = bdec[lane + e * 64];

#pragma unroll 4
    for (int k = 0; k < K_SEL; ++k) {
        float vkv = __shfl(lv, k);
        int   jj  = __shfl(li, k);
        const float* wr = WdT + (size_t)jj * D_IN + lane;
#pragma unroll
        for (int e = 0; e < 10; ++e) acc[e] = fmaf(vkv, wr[e * 64], acc[e]);
    }
    float* out = recon + (size_t)r * D_IN + lane;
#pragma unroll
    for (int e = 0; e < 10; ++e) out[e * 64] = acc[e];

    // zero sparse row, wait stores, scatter selected (val 0 slots are inert)
    float4 z; z.x = z.y = z.z = z.w = 0.f;
    float4* srow4 = (float4*)(sparse + (size_t)r * D_LAT);
#pragma unroll
    for (int e = 0; e < 10; ++e) srow4[lane + e * 64] = z;
    __builtin_amdgcn_s_waitcnt(0);
    if (lane < K_SEL && lv != 0.f) sparse[(size_t)r * D_LAT + li] = lv;
}

extern "C" void kernel_launch(void* const* d_in, const int* in_sizes, int n_in,
                              void* d_out, int out_size, void* d_ws, size_t ws_size,
                              hipStream_t stream) {
    const float* x     = (const float*)d_in[0];
    const float* W_enc = (const float*)d_in[1];
    const float* b_enc = (const float*)d_in[2];
    const float* W_dec = (const float*)d_in[3];
    const float* b_dec = (const float*)d_in[4];

    float* recon  = (float*)d_out;                                  // [B][640]
    float* sparse = (float*)d_out + (size_t)B_ROWS * D_IN;          // [B][2560]

    // xB (bf16 copy of x, 84MB) parks in the recon region (167MB): recon is only
    // written by dec_kernel, which runs after enc_mfma has consumed xB.
    ushort* xB = (ushort*)recon;

    char* ws = (char*)d_ws;
    size_t off = 0;
    float*  WdT  = (float*) (ws + off); off += (size_t)D_LAT * D_IN * 4;    // 6.55 MB
    ushort* WeB  = (ushort*)(ws + off); off += (size_t)D_LAT * D_IN * 2;    // 3.28 MB
    int*    cidx = (int*)   (ws + off); off += (size_t)B_ROWS * CCAP * 4;   // 16.8 MB
    float*  cval = (float*) (ws + off); off += (size_t)B_ROWS * CCAP * 4;   // 16.8 MB
    int*    ccnt = (int*)   (ws + off); off += (size_t)B_ROWS * 4;          // 0.26 MB
    float*  vals = (float*) (ws + off); off += (size_t)B_ROWS * K_SEL * 4;  // 8.4 MB
    int*    idxs = (int*)   (ws + off);                                     // 8.4 MB

    hipLaunchKernelGGL(cvt_bf16, dim3((size_t)B_ROWS * D_IN / 1024), dim3(256), 0, stream,
                       x, xB);
    hipLaunchKernelGGL(cvt_bf16, dim3((size_t)D_LAT * D_IN / 1024), dim3(256), 0, stream,
                       W_enc, WeB);
    hipLaunchKernelGGL(transpose_wdec, dim3(D_LAT / 32, D_IN / 32), dim3(256), 0, stream,
                       W_dec, WdT);
    hipLaunchKernelGGL(enc_mfma, dim3(D_LAT / 128, B_ROWS / 128), dim3(256), 0, stream,
                       xB, WeB, b_enc, sparse);
    hipLaunchKernelGGL(topk_cand, dim3(B_ROWS / 4), dim3(256), 0, stream,
                       sparse, cidx, cval, ccnt);
    hipLaunchKernelGGL(refine_sel, dim3(B_ROWS / 4), dim3(256), 0, stream,
                       x, W_enc, b_enc, cidx, cval, ccnt, vals, idxs);
    hipLaunchKernelGGL(dec_kernel, dim3(B_ROWS / 4), dim3(256), 0, stream,
                       vals, idxs, WdT, b_dec, recon, sparse);
}

// Round 22
// 1098.450 us; speedup vs baseline: 4.1349x; 1.2153x over previous
//
#include <hip/hip_runtime.h>
#include <cstdint>

#define B_ROWS 65536
#define D_IN   640
#define D_LAT  2560
#define K_SEL  32
#define NCAND  48
#define CCAP   64      // candidate capacity per row
#define DELTA  0.04f   // ambiguity half-window: covers bf16 ulp (0.0156) + GEMM err
// np-exact K-panel boundaries (OpenBLAS SKYLAKEX Q=192): 192+192+128+128
#define P1 192
#define P2 384
#define P3 512

typedef __attribute__((ext_vector_type(8))) short short8;
typedef __attribute__((ext_vector_type(4))) float f32x4;

static __device__ __forceinline__ ushort f2bf(float f) {
    uint32_t u = __float_as_uint(f);
    u += 0x7fffu + ((u >> 16) & 1u);   // round-to-nearest-even
    return (ushort)(u >> 16);
}
static __device__ __forceinline__ float b2f(ushort u) {
    return __uint_as_float((uint32_t)u << 16);
}

// ---------------- generic fp32 -> bf16 convert (4 elems/thread) -------------------
__global__ __launch_bounds__(256) void cvt_bf16(const float* __restrict__ src,
                                                ushort* __restrict__ dst) {
    const size_t i = ((size_t)blockIdx.x * 256 + threadIdx.x) * 4;
    float4 v = *(const float4*)(src + i);
    ushort4 o;
    o.x = f2bf(v.x); o.y = f2bf(v.y); o.z = f2bf(v.z); o.w = f2bf(v.w);
    *(ushort4*)(dst + i) = o;
}

// ---------------- W_dec transpose -> bf16: [640][2560] -> WdTb [2560][640] -------
__global__ __launch_bounds__(256) void transpose_wdec(const float* __restrict__ Wd,
                                                      ushort* __restrict__ WdTb) {
    __shared__ float t[32][33];
    const int j0 = blockIdx.x * 32;
    const int i0 = blockIdx.y * 32;
    const int tx = threadIdx.x & 31, ty = threadIdx.x >> 5;
#pragma unroll
    for (int q = 0; q < 4; ++q)
        t[ty + 8 * q][tx] = Wd[(size_t)(i0 + ty + 8 * q) * D_LAT + j0 + tx];
    __syncthreads();
#pragma unroll
    for (int q = 0; q < 4; ++q)
        WdTb[(size_t)(j0 + ty + 8 * q) * D_IN + i0 + tx] = f2bf(t[tx][ty + 8 * q]);
}

// ---------------- bf16 MFMA filter GEMM -> bf16 latents --------------------------
__global__ __launch_bounds__(256, 3) void enc_mfma(const ushort* __restrict__ A,
                                                   const ushort* __restrict__ Wb,
                                                   const float* __restrict__ bias,
                                                   ushort* __restrict__ C) {
    __shared__ ushort Al[128][40];   // pad 32->40 (80B row): 2-way conflicts = free
    __shared__ ushort Bl[128][40];
    const int tid = threadIdx.x;
    const int n0 = blockIdx.x * 128;
    const int m0 = blockIdx.y * 128;
    const int srow = tid >> 1, shalf = tid & 1;
    const ushort* Ap = A  + (size_t)(m0 + srow) * D_IN + shalf * 16;
    const ushort* Bp = Wb + (size_t)(n0 + srow) * D_IN + shalf * 16;

    const int w = tid >> 6, l = tid & 63;
    const int wm = w >> 1, wn = w & 1;
    const int fr = l & 15, ko = l >> 4;

    f32x4 acc[4][4];
#pragma unroll
    for (int i = 0; i < 4; ++i)
#pragma unroll
        for (int j = 0; j < 4; ++j) acc[i][j] = (f32x4)0.0f;

    uint4 a0, a1, b0, b1;
#define LOADT(KT)                                                    \
    {                                                                \
        const uint* ap = (const uint*)(Ap + (KT) * 32);              \
        a0 = *(const uint4*)(ap);                                    \
        a1 = *(const uint4*)(ap + 4);                                \
        const uint* bp = (const uint*)(Bp + (KT) * 32);              \
        b0 = *(const uint4*)(bp);                                    \
        b1 = *(const uint4*)(bp + 4);                                \
    }

    LOADT(0);
    const int NT = D_IN / 32;   // 20
    for (int kt = 0; kt < NT; ++kt) {
        *(uint4*)&Al[srow][shalf * 16]     = a0;
        *(uint4*)&Al[srow][shalf * 16 + 8] = a1;
        *(uint4*)&Bl[srow][shalf * 16]     = b0;
        *(uint4*)&Bl[srow][shalf * 16 + 8] = b1;
        __syncthreads();
        if (kt + 1 < NT) LOADT(kt + 1);

        short8 af[4], bf[4];
#pragma unroll
        for (int fm = 0; fm < 4; ++fm)
            af[fm] = *(const short8*)&Al[wm * 64 + fm * 16 + fr][ko * 8];
#pragma unroll
        for (int fn = 0; fn < 4; ++fn)
            bf[fn] = *(const short8*)&Bl[wn * 64 + fn * 16 + fr][ko * 8];
#pragma unroll
        for (int fm = 0; fm < 4; ++fm)
#pragma unroll
            for (int fn = 0; fn < 4; ++fn)
                acc[fm][fn] = __builtin_amdgcn_mfma_f32_16x16x32_bf16(
                    af[fm], bf[fn], acc[fm][fn], 0, 0, 0);
        __syncthreads();
    }
#undef LOADT

#pragma unroll
    for (int fn = 0; fn < 4; ++fn) {
        const int col = n0 + wn * 64 + fn * 16 + fr;
        const float bb = bias[col];
#pragma unroll
        for (int fm = 0; fm < 4; ++fm) {
#pragma unroll
            for (int j = 0; j < 4; ++j) {
                const int row = m0 + wm * 64 + fm * 16 + ko * 4 + j;
                C[(size_t)row * D_LAT + col] = f2bf(acc[fm][fn][j] + bb);
            }
        }
    }
}

// ---------------- Candidate select by threshold (wave-per-row, bf16 latents) -----
__global__ __launch_bounds__(256) void topk_cand(const ushort* __restrict__ lat,
                                                 int* __restrict__ cidx,
                                                 float* __restrict__ cval,
                                                 int* __restrict__ ccnt) {
    const int wv = threadIdx.x >> 6, lane = threadIdx.x & 63;
    const int r = blockIdx.x * 4 + wv;
    const ushort* row = lat + (size_t)r * D_LAT;

    float4 v[10];
#pragma unroll
    for (int e = 0; e < 10; ++e) {
        const ushort4 u = *(const ushort4*)(row + e * 256 + lane * 4);
        v[e].x = b2f(u.x); v[e].y = b2f(u.y); v[e].z = b2f(u.z); v[e].w = b2f(u.w);
    }

    float mx = v[0].x;
#pragma unroll
    for (int e = 0; e < 10; ++e) {
        mx = fmaxf(mx, fmaxf(fmaxf(v[e].x, v[e].y), fmaxf(v[e].z, v[e].w)));
    }
#pragma unroll
    for (int off = 1; off < 64; off <<= 1) mx = fmaxf(mx, __shfl_xor(mx, off));

    auto countGt = [&](float t) -> int {
        int c = 0;
#pragma unroll
        for (int e = 0; e < 10; ++e)
            c += (v[e].x > t) + (v[e].y > t) + (v[e].z > t) + (v[e].w > t);
#pragma unroll
        for (int off = 1; off < 64; off <<= 1) c += __shfl_xor(c, off);
        return c;
    };

    float lo = mx - 2.0f;
    int clo = countGt(lo);
    if (clo < NCAND) { lo = mx - 4.0f; clo = countGt(lo); }
    if (clo < NCAND) { lo = mx - 16.0f; clo = countGt(lo); }   // paranoia tier
    float hi = mx;
    for (int it = 0; it < 28 && clo > CCAP; ++it) {
        const float mid = 0.5f * (lo + hi);
        const int c = countGt(mid);
        if (c >= NCAND) { lo = mid; clo = c; } else hi = mid;
    }

    int base = 0;
#pragma unroll
    for (int e = 0; e < 10; ++e) {
#pragma unroll
        for (int q = 0; q < 4; ++q) {
            const float val = (q == 0) ? v[e].x : (q == 1) ? v[e].y
                            : (q == 2) ? v[e].z : v[e].w;
            const bool take = val > lo;
            const uint64_t m = __ballot(take);
            const int pos = base + __popcll(m & ((1ull << lane) - 1ull));
            if (take && pos < CCAP) {
                cidx[(size_t)r * CCAP + pos] = e * 256 + lane * 4 + q;
                cval[(size_t)r * CCAP + pos] = val;
            }
            base += __popcll(m);
        }
    }
    if (lane == 0) ccnt[r] = (base < CCAP) ? base : CCAP;
}

// ---------------- Boundary-window refine + select (wave-per-row) -----------------
// Identical logic to R21 (passing); only DELTA widened for bf16 latents.
__global__ __launch_bounds__(256, 4) void refine_sel(const float* __restrict__ x,
                                                     const float* __restrict__ We,
                                                     const float* __restrict__ be,
                                                     const int* __restrict__ cidx,
                                                     const float* __restrict__ cval,
                                                     const int* __restrict__ ccnt,
                                                     float* __restrict__ vals,
                                                     int* __restrict__ idxs) {
    const int wv = threadIdx.x >> 6, lane = threadIdx.x & 63;
    const int r = blockIdx.x * 4 + wv;

    __shared__ float xs[4][656];     // panel bases 0,196,392,524 (banks 0,4,8,12)
    __shared__ int   winj[4][CCAP];
    __shared__ float exv[4][CCAP];

    const int cnt = ccnt[r];

    if (lane < K_SEL) {
        vals[(size_t)r * K_SEL + lane] = 0.f;
        idxs[(size_t)r * K_SEL + lane] = 0;
    }

    for (int i = lane; i < D_IN; i += 64) {
        const int p  = (i >= P3) ? 3 : (i >= P2) ? 2 : (i >= P1) ? 1 : 0;
        const int kb = (p == 0) ? 0 : (p == 1) ? P1  : (p == 2) ? P2  : P3;
        const int pb = (p == 0) ? 0 : (p == 1) ? 196 : (p == 2) ? 392 : 524;
        xs[wv][pb + i - kb] = x[(size_t)r * D_IN + i];
    }

    float v = -__builtin_inff(); int j = 0x7fffffff;
    if (lane < cnt) {
        j = cidx[(size_t)r * CCAP + lane];
        v = cval[(size_t)r * CCAP + lane];
    }

    float mxv = v, mnv = (lane < cnt) ? v : __builtin_inff();
#pragma unroll
    for (int off = 1; off < 64; off <<= 1) {
        mxv = fmaxf(mxv, __shfl_xor(mxv, off));
        mnv = fminf(mnv, __shfl_xor(mnv, off));
    }
    auto cgt = [&](float t) -> int {
        int c = (v > t) ? 1 : 0;
#pragma unroll
        for (int off = 1; off < 64; off <<= 1) c += __shfl_xor(c, off);
        return c;
    };
    float blo = mnv - 0.01f, bhi = mxv;
    for (int it = 0; it < 20; ++it) {
        const float mid = 0.5f * (blo + bhi);
        if (cgt(mid) >= K_SEL) blo = mid; else bhi = mid;
    }
    const float v32a = blo;
    const bool sure_in = (lane < cnt) && (v > v32a + DELTA);
    const bool inwin   = (lane < cnt) && !sure_in && (v > v32a - DELTA);
    const int n_in = __popcll(__ballot(sure_in));
    const uint64_t wm = __ballot(inwin);
    const int wcnt = __popcll(wm);
    if (inwin) winj[wv][__popcll(wm & ((1ull << lane) - 1ull))] = j;

    __syncthreads();

    for (int p0 = 0; p0 < wcnt; p0 += 16) {
        const int rank = p0 + (lane >> 2), pnl = lane & 3;
        float a = 0.f; int jj = 0;
        if (rank < wcnt) {
            jj = winj[wv][rank];
            const int k0 = (pnl == 0) ? 0 : (pnl == 1) ? P1  : (pnl == 2) ? P2  : P3;
            const int k1 = (pnl == 0) ? P1 : (pnl == 1) ? P2 : (pnl == 2) ? P3 : D_IN;
            const int pb = (pnl == 0) ? 0 : (pnl == 1) ? 196 : (pnl == 2) ? 392 : 524;
            const float4* wp4 = (const float4*)(We + (size_t)jj * D_IN + k0);
            const float4* xp4 = (const float4*)&xs[wv][pb];
            const int nb = (k1 - k0) >> 4;   // 64B bursts: 12/12/8/8
#pragma unroll 2
            for (int b = 0; b < nb; ++b) {
                const float4 w0 = wp4[b * 4 + 0], w1 = wp4[b * 4 + 1];
                const float4 w2 = wp4[b * 4 + 2], w3 = wp4[b * 4 + 3];
                const float4 x0 = xp4[b * 4 + 0], x1 = xp4[b * 4 + 1];
                const float4 x2 = xp4[b * 4 + 2], x3 = xp4[b * 4 + 3];
                a = fmaf(w0.x, x0.x, a); a = fmaf(w0.y, x0.y, a);
                a = fmaf(w0.z, x0.z, a); a = fmaf(w0.w, x0.w, a);
                a = fmaf(w1.x, x1.x, a); a = fmaf(w1.y, x1.y, a);
                a = fmaf(w1.z, x1.z, a); a = fmaf(w1.w, x1.w, a);
                a = fmaf(w2.x, x2.x, a); a = fmaf(w2.y, x2.y, a);
                a = fmaf(w2.z, x2.z, a); a = fmaf(w2.w, x2.w, a);
                a = fmaf(w3.x, x3.x, a); a = fmaf(w3.y, x3.y, a);
                a = fmaf(w3.z, x3.z, a); a = fmaf(w3.w, x3.w, a);
            }
        }
        const int gb = lane & ~3;
        const float a0 = __shfl(a, gb + 0), a1 = __shfl(a, gb + 1);
        const float a2 = __shfl(a, gb + 2), a3 = __shfl(a, gb + 3);
        if (pnl == 0 && rank < wcnt)
            exv[wv][rank] = (((a0 + a1) + a2) + a3) + be[jj];
    }
    __syncthreads();

    const uint64_t sm = __ballot(sure_in);
    if (sure_in) {
        const int pos = __popcll(sm & ((1ull << lane) - 1ull));
        vals[(size_t)r * K_SEL + pos] = v;
        idxs[(size_t)r * K_SEL + pos] = j;
    }

    float ev = (lane < wcnt) ? exv[wv][lane] : -__builtin_inff();
    int   ej = (lane < wcnt) ? winj[wv][lane] : 0x7fffffff;
    int need = K_SEL - n_in;
    if (need > wcnt) need = wcnt;    // defensive
    for (int t = 0; t < need; ++t) {
        float bv = ev; int bi = ej;
#pragma unroll
        for (int off = 1; off < 64; off <<= 1) {
            float ov = __shfl_xor(bv, off);
            int   oi = __shfl_xor(bi, off);
            if (ov > bv || (ov == bv && oi < bi)) { bv = ov; bi = oi; }
        }
        if (ej == bi && ej != 0x7fffffff) {   // unique winner lane
            vals[(size_t)r * K_SEL + n_in + t] = ev;
            idxs[(size_t)r * K_SEL + n_in + t] = ej;
            ev = -__builtin_inff(); ej = 0x7fffffff;
        }
    }
}

// ---------------- Decoder + sparse writeback (bf16 WdT, L2-resident) -------------
__global__ __launch_bounds__(256) void dec_kernel(const float* __restrict__ vals,
                                                  const int* __restrict__ idxs,
                                                  const ushort* __restrict__ WdTb,
                                                  const float* __restrict__ bdec,
                                                  float* __restrict__ recon,
                                                  float* __restrict__ sparse) {
    const int wave = threadIdx.x >> 6, lane = threadIdx.x & 63;
    const int r = blockIdx.x * 4 + wave;

    float lv = 0.f; int li = 0;
    if (lane < K_SEL) {
        lv = vals[(size_t)r * K_SEL + lane];
        li = idxs[(size_t)r * K_SEL + lane];
        li = (li < 0) ? 0 : ((li >= D_LAT) ? D_LAT - 1 : li);   // defensive clamp
    }
    float acc[10];
#pragma unroll
    for (int e = 0; e < 10; ++e) acc[e] = bdec[lane + e * 64];

#pragma unroll 4
    for (int k = 0; k < K_SEL; ++k) {
        float vkv = __shfl(lv, k);
        int   jj  = __shfl(li, k);
        const ushort* wr = WdTb + (size_t)jj * D_IN + lane;
#pragma unroll
        for (int e = 0; e < 10; ++e) acc[e] = fmaf(vkv, b2f(wr[e * 64]), acc[e]);
    }
    float* out = recon + (size_t)r * D_IN + lane;
#pragma unroll
    for (int e = 0; e < 10; ++e) out[e * 64] = acc[e];

    // zero sparse row, wait stores, scatter selected (val 0 slots are inert)
    float4 z; z.x = z.y = z.z = z.w = 0.f;
    float4* srow4 = (float4*)(sparse + (size_t)r * D_LAT);
#pragma unroll
    for (int e = 0; e < 10; ++e) srow4[lane + e * 64] = z;
    __builtin_amdgcn_s_waitcnt(0);
    if (lane < K_SEL && lv != 0.f) sparse[(size_t)r * D_LAT + li] = lv;
}

extern "C" void kernel_launch(void* const* d_in, const int* in_sizes, int n_in,
                              void* d_out, int out_size, void* d_ws, size_t ws_size,
                              hipStream_t stream) {
    const float* x     = (const float*)d_in[0];
    const float* W_enc = (const float*)d_in[1];
    const float* b_enc = (const float*)d_in[2];
    const float* W_dec = (const float*)d_in[3];
    const float* b_dec = (const float*)d_in[4];

    float* recon  = (float*)d_out;                                  // [B][640]
    float* sparse = (float*)d_out + (size_t)B_ROWS * D_IN;          // [B][2560]

    // xB (bf16 x, 84MB) parks in recon region; latB (bf16 latents, 336MB) parks in
    // the sparse region (both consumed before dec_kernel writes those regions).
    ushort* xB   = (ushort*)recon;
    ushort* latB = (ushort*)sparse;

    char* ws = (char*)d_ws;
    size_t off = 0;
    ushort* WdTb = (ushort*)(ws + off); off += (size_t)D_LAT * D_IN * 2;    // 3.28 MB
    ushort* WeB  = (ushort*)(ws + off); off += (size_t)D_LAT * D_IN * 2;    // 3.28 MB
    int*    cidx = (int*)   (ws + off); off += (size_t)B_ROWS * CCAP * 4;   // 16.8 MB
    float*  cval = (float*) (ws + off); off += (size_t)B_ROWS * CCAP * 4;   // 16.8 MB
    int*    ccnt = (int*)   (ws + off); off += (size_t)B_ROWS * 4;          // 0.26 MB
    float*  vals = (float*) (ws + off); off += (size_t)B_ROWS * K_SEL * 4;  // 8.4 MB
    int*    idxs = (int*)   (ws + off);                                     // 8.4 MB

    hipLaunchKernelGGL(cvt_bf16, dim3((size_t)B_ROWS * D_IN / 1024), dim3(256), 0, stream,
                       x, xB);
    hipLaunchKernelGGL(cvt_bf16, dim3((size_t)D_LAT * D_IN / 1024), dim3(256), 0, stream,
                       W_enc, WeB);
    hipLaunchKernelGGL(transpose_wdec, dim3(D_LAT / 32, D_IN / 32), dim3(256), 0, stream,
                       W_dec, WdTb);
    hipLaunchKernelGGL(enc_mfma, dim3(D_LAT / 128, B_ROWS / 128), dim3(256), 0, stream,
                       xB, WeB, b_enc, latB);
    hipLaunchKernelGGL(topk_cand, dim3(B_ROWS / 4), dim3(256), 0, stream,
                       latB, cidx, cval, ccnt);
    hipLaunchKernelGGL(refine_sel, dim3(B_ROWS / 4), dim3(256), 0, stream,
                       x, W_enc, b_enc, cidx, cval, ccnt, vals, idxs);
    hipLaunchKernelGGL(dec_kernel, dim3(B_ROWS / 4), dim3(256), 0, stream,
                       vals, idxs, WdTb, b_dec, recon, sparse);
}

// Round 23
// 1079.426 us; speedup vs baseline: 4.2078x; 1.0176x over previous
//
#include <hip/hip_runtime.h>
#include <cstdint>

#define B_ROWS 65536
#define D_IN   640
#define D_LAT  2560
#define K_SEL  32
#define NCAND  48
#define CCAP   64      // candidate capacity per row
#define DELTA  0.04f   // ambiguity half-window: covers bf16 ulp (0.0156) + GEMM err
// np-exact K-panel boundaries (OpenBLAS SKYLAKEX Q=192): 192+192+128+128
#define P1 192
#define P2 384
#define P3 512

typedef __attribute__((ext_vector_type(8))) short short8;
typedef __attribute__((ext_vector_type(4))) float f32x4;

static __device__ __forceinline__ ushort f2bf(float f) {
    uint32_t u = __float_as_uint(f);
    u += 0x7fffu + ((u >> 16) & 1u);   // round-to-nearest-even
    return (ushort)(u >> 16);
}
static __device__ __forceinline__ float b2f(ushort u) {
    return __uint_as_float((uint32_t)u << 16);
}

// ---------------- generic fp32 -> bf16 convert (4 elems/thread) -------------------
__global__ __launch_bounds__(256) void cvt_bf16(const float* __restrict__ src,
                                                ushort* __restrict__ dst) {
    const size_t i = ((size_t)blockIdx.x * 256 + threadIdx.x) * 4;
    float4 v = *(const float4*)(src + i);
    ushort4 o;
    o.x = f2bf(v.x); o.y = f2bf(v.y); o.z = f2bf(v.z); o.w = f2bf(v.w);
    *(ushort4*)(dst + i) = o;
}

// ---------------- W_dec transpose -> bf16: [640][2560] -> WdTb [2560][640] -------
__global__ __launch_bounds__(256) void transpose_wdec(const float* __restrict__ Wd,
                                                      ushort* __restrict__ WdTb) {
    __shared__ float t[32][33];
    const int j0 = blockIdx.x * 32;
    const int i0 = blockIdx.y * 32;
    const int tx = threadIdx.x & 31, ty = threadIdx.x >> 5;
#pragma unroll
    for (int q = 0; q < 4; ++q)
        t[ty + 8 * q][tx] = Wd[(size_t)(i0 + ty + 8 * q) * D_LAT + j0 + tx];
    __syncthreads();
#pragma unroll
    for (int q = 0; q < 4; ++q)
        WdTb[(size_t)(j0 + ty + 8 * q) * D_IN + i0 + tx] = f2bf(t[tx][ty + 8 * q]);
}

// ---------------- bf16 MFMA filter GEMM -> bf16 latents --------------------------
__global__ __launch_bounds__(256, 3) void enc_mfma(const ushort* __restrict__ A,
                                                   const ushort* __restrict__ Wb,
                                                   const float* __restrict__ bias,
                                                   ushort* __restrict__ C) {
    __shared__ ushort Al[128][40];   // pad 32->40 (80B row): 2-way conflicts = free
    __shared__ ushort Bl[128][40];
    const int tid = threadIdx.x;
    const int n0 = blockIdx.x * 128;
    const int m0 = blockIdx.y * 128;
    const int srow = tid >> 1, shalf = tid & 1;
    const ushort* Ap = A  + (size_t)(m0 + srow) * D_IN + shalf * 16;
    const ushort* Bp = Wb + (size_t)(n0 + srow) * D_IN + shalf * 16;

    const int w = tid >> 6, l = tid & 63;
    const int wm = w >> 1, wn = w & 1;
    const int fr = l & 15, ko = l >> 4;

    f32x4 acc[4][4];
#pragma unroll
    for (int i = 0; i < 4; ++i)
#pragma unroll
        for (int j = 0; j < 4; ++j) acc[i][j] = (f32x4)0.0f;

    uint4 a0, a1, b0, b1;
#define LOADT(KT)                                                    \
    {                                                                \
        const uint* ap = (const uint*)(Ap + (KT) * 32);              \
        a0 = *(const uint4*)(ap);                                    \
        a1 = *(const uint4*)(ap + 4);                                \
        const uint* bp = (const uint*)(Bp + (KT) * 32);              \
        b0 = *(const uint4*)(bp);                                    \
        b1 = *(const uint4*)(bp + 4);                                \
    }

    LOADT(0);
    const int NT = D_IN / 32;   // 20
    for (int kt = 0; kt < NT; ++kt) {
        *(uint4*)&Al[srow][shalf * 16]     = a0;
        *(uint4*)&Al[srow][shalf * 16 + 8] = a1;
        *(uint4*)&Bl[srow][shalf * 16]     = b0;
        *(uint4*)&Bl[srow][shalf * 16 + 8] = b1;
        __syncthreads();
        if (kt + 1 < NT) LOADT(kt + 1);

        short8 af[4], bf[4];
#pragma unroll
        for (int fm = 0; fm < 4; ++fm)
            af[fm] = *(const short8*)&Al[wm * 64 + fm * 16 + fr][ko * 8];
#pragma unroll
        for (int fn = 0; fn < 4; ++fn)
            bf[fn] = *(const short8*)&Bl[wn * 64 + fn * 16 + fr][ko * 8];
#pragma unroll
        for (int fm = 0; fm < 4; ++fm)
#pragma unroll
            for (int fn = 0; fn < 4; ++fn)
                acc[fm][fn] = __builtin_amdgcn_mfma_f32_16x16x32_bf16(
                    af[fm], bf[fn], acc[fm][fn], 0, 0, 0);
        __syncthreads();
    }
#undef LOADT

#pragma unroll
    for (int fn = 0; fn < 4; ++fn) {
        const int col = n0 + wn * 64 + fn * 16 + fr;
        const float bb = bias[col];
#pragma unroll
        for (int fm = 0; fm < 4; ++fm) {
#pragma unroll
            for (int j = 0; j < 4; ++j) {
                const int row = m0 + wm * 64 + fm * 16 + ko * 4 + j;
                C[(size_t)row * D_LAT + col] = f2bf(acc[fm][fn][j] + bb);
            }
        }
    }
}

// ---------------- Candidate select by threshold (wave-per-row, bf16 latents) -----
// 16B loads: lane owns 8 consecutive bf16 per chunk, 5 chunks of 512.
__global__ __launch_bounds__(256) void topk_cand(const ushort* __restrict__ lat,
                                                 int* __restrict__ cidx,
                                                 float* __restrict__ cval,
                                                 int* __restrict__ ccnt) {
    const int wv = threadIdx.x >> 6, lane = threadIdx.x & 63;
    const int r = blockIdx.x * 4 + wv;
    const ushort* row = lat + (size_t)r * D_LAT;

    float v[5][8];
#pragma unroll
    for (int e = 0; e < 5; ++e) {
        const uint4 u = *(const uint4*)(row + e * 512 + lane * 8);
        v[e][0] = __uint_as_float(u.x << 16);
        v[e][1] = __uint_as_float(u.x & 0xffff0000u);
        v[e][2] = __uint_as_float(u.y << 16);
        v[e][3] = __uint_as_float(u.y & 0xffff0000u);
        v[e][4] = __uint_as_float(u.z << 16);
        v[e][5] = __uint_as_float(u.z & 0xffff0000u);
        v[e][6] = __uint_as_float(u.w << 16);
        v[e][7] = __uint_as_float(u.w & 0xffff0000u);
    }

    float mx = v[0][0];
#pragma unroll
    for (int e = 0; e < 5; ++e)
#pragma unroll
        for (int t = 0; t < 8; ++t) mx = fmaxf(mx, v[e][t]);
#pragma unroll
    for (int off = 1; off < 64; off <<= 1) mx = fmaxf(mx, __shfl_xor(mx, off));

    auto countGt = [&](float t) -> int {
        int c = 0;
#pragma unroll
        for (int e = 0; e < 5; ++e)
#pragma unroll
            for (int q = 0; q < 8; ++q) c += (v[e][q] > t);
#pragma unroll
        for (int off = 1; off < 64; off <<= 1) c += __shfl_xor(c, off);
        return c;
    };

    float lo = mx - 2.0f;
    int clo = countGt(lo);
    if (clo < NCAND) { lo = mx - 4.0f; clo = countGt(lo); }
    if (clo < NCAND) { lo = mx - 16.0f; clo = countGt(lo); }   // paranoia tier
    float hi = mx;
    for (int it = 0; it < 28 && clo > CCAP; ++it) {
        const float mid = 0.5f * (lo + hi);
        const int c = countGt(mid);
        if (c >= NCAND) { lo = mid; clo = c; } else hi = mid;
    }

    int base = 0;
#pragma unroll
    for (int e = 0; e < 5; ++e) {
#pragma unroll
        for (int q = 0; q < 8; ++q) {
            const float val = v[e][q];
            const bool take = val > lo;
            const uint64_t m = __ballot(take);
            const int pos = base + __popcll(m & ((1ull << lane) - 1ull));
            if (take && pos < CCAP) {
                cidx[(size_t)r * CCAP + pos] = e * 512 + lane * 8 + q;
                cval[(size_t)r * CCAP + pos] = val;
            }
            base += __popcll(m);
        }
    }
    if (lane == 0) ccnt[r] = (base < CCAP) ? base : CCAP;
}

// ---------------- Boundary-window refine + select (wave-per-row) -----------------
__global__ __launch_bounds__(256, 4) void refine_sel(const float* __restrict__ x,
                                                     const float* __restrict__ We,
                                                     const float* __restrict__ be,
                                                     const int* __restrict__ cidx,
                                                     const float* __restrict__ cval,
                                                     const int* __restrict__ ccnt,
                                                     float* __restrict__ vals,
                                                     int* __restrict__ idxs) {
    const int wv = threadIdx.x >> 6, lane = threadIdx.x & 63;
    const int r = blockIdx.x * 4 + wv;

    __shared__ float xs[4][656];     // panel bases 0,196,392,524 (banks 0,4,8,12)
    __shared__ int   winj[4][CCAP];
    __shared__ float exv[4][CCAP];

    const int cnt = ccnt[r];

    if (lane < K_SEL) {
        vals[(size_t)r * K_SEL + lane] = 0.f;
        idxs[(size_t)r * K_SEL + lane] = 0;
    }

    for (int i = lane; i < D_IN; i += 64) {
        const int p  = (i >= P3) ? 3 : (i >= P2) ? 2 : (i >= P1) ? 1 : 0;
        const int kb = (p == 0) ? 0 : (p == 1) ? P1  : (p == 2) ? P2  : P3;
        const int pb = (p == 0) ? 0 : (p == 1) ? 196 : (p == 2) ? 392 : 524;
        xs[wv][pb + i - kb] = x[(size_t)r * D_IN + i];
    }

    float v = -__builtin_inff(); int j = 0x7fffffff;
    if (lane < cnt) {
        j = cidx[(size_t)r * CCAP + lane];
        v = cval[(size_t)r * CCAP + lane];
    }

    float mxv = v, mnv = (lane < cnt) ? v : __builtin_inff();
#pragma unroll
    for (int off = 1; off < 64; off <<= 1) {
        mxv = fmaxf(mxv, __shfl_xor(mxv, off));
        mnv = fminf(mnv, __shfl_xor(mnv, off));
    }
    auto cgt = [&](float t) -> int {
        int c = (v > t) ? 1 : 0;
#pragma unroll
        for (int off = 1; off < 64; off <<= 1) c += __shfl_xor(c, off);
        return c;
    };
    float blo = mnv - 0.01f, bhi = mxv;
    for (int it = 0; it < 20; ++it) {
        const float mid = 0.5f * (blo + bhi);
        if (cgt(mid) >= K_SEL) blo = mid; else bhi = mid;
    }
    const float v32a = blo;
    const bool sure_in = (lane < cnt) && (v > v32a + DELTA);
    const bool inwin   = (lane < cnt) && !sure_in && (v > v32a - DELTA);
    const int n_in = __popcll(__ballot(sure_in));
    const uint64_t wm = __ballot(inwin);
    const int wcnt = __popcll(wm);
    if (inwin) winj[wv][__popcll(wm & ((1ull << lane) - 1ull))] = j;

    __syncthreads();

    for (int p0 = 0; p0 < wcnt; p0 += 16) {
        const int rank = p0 + (lane >> 2), pnl = lane & 3;
        float a = 0.f; int jj = 0;
        if (rank < wcnt) {
            jj = winj[wv][rank];
            const int k0 = (pnl == 0) ? 0 : (pnl == 1) ? P1  : (pnl == 2) ? P2  : P3;
            const int k1 = (pnl == 0) ? P1 : (pnl == 1) ? P2 : (pnl == 2) ? P3 : D_IN;
            const int pb = (pnl == 0) ? 0 : (pnl == 1) ? 196 : (pnl == 2) ? 392 : 524;
            const float4* wp4 = (const float4*)(We + (size_t)jj * D_IN + k0);
            const float4* xp4 = (const float4*)&xs[wv][pb];
            const int nb = (k1 - k0) >> 4;   // 64B bursts: 12/12/8/8
#pragma unroll 2
            for (int b = 0; b < nb; ++b) {
                const float4 w0 = wp4[b * 4 + 0], w1 = wp4[b * 4 + 1];
                const float4 w2 = wp4[b * 4 + 2], w3 = wp4[b * 4 + 3];
                const float4 x0 = xp4[b * 4 + 0], x1 = xp4[b * 4 + 1];
                const float4 x2 = xp4[b * 4 + 2], x3 = xp4[b * 4 + 3];
                a = fmaf(w0.x, x0.x, a); a = fmaf(w0.y, x0.y, a);
                a = fmaf(w0.z, x0.z, a); a = fmaf(w0.w, x0.w, a);
                a = fmaf(w1.x, x1.x, a); a = fmaf(w1.y, x1.y, a);
                a = fmaf(w1.z, x1.z, a); a = fmaf(w1.w, x1.w, a);
                a = fmaf(w2.x, x2.x, a); a = fmaf(w2.y, x2.y, a);
                a = fmaf(w2.z, x2.z, a); a = fmaf(w2.w, x2.w, a);
                a = fmaf(w3.x, x3.x, a); a = fmaf(w3.y, x3.y, a);
                a = fmaf(w3.z, x3.z, a); a = fmaf(w3.w, x3.w, a);
            }
        }
        const int gb = lane & ~3;
        const float a0 = __shfl(a, gb + 0), a1 = __shfl(a, gb + 1);
        const float a2 = __shfl(a, gb + 2), a3 = __shfl(a, gb + 3);
        if (pnl == 0 && rank < wcnt)
            exv[wv][rank] = (((a0 + a1) + a2) + a3) + be[jj];
    }
    __syncthreads();

    const uint64_t sm = __ballot(sure_in);
    if (sure_in) {
        const int pos = __popcll(sm & ((1ull << lane) - 1ull));
        vals[(size_t)r * K_SEL + pos] = v;
        idxs[(size_t)r * K_SEL + pos] = j;
    }

    float ev = (lane < wcnt) ? exv[wv][lane] : -__builtin_inff();
    int   ej = (lane < wcnt) ? winj[wv][lane] : 0x7fffffff;
    int need = K_SEL - n_in;
    if (need > wcnt) need = wcnt;    // defensive
    for (int t = 0; t < need; ++t) {
        float bv = ev; int bi = ej;
#pragma unroll
        for (int off = 1; off < 64; off <<= 1) {
            float ov = __shfl_xor(bv, off);
            int   oi = __shfl_xor(bi, off);
            if (ov > bv || (ov == bv && oi < bi)) { bv = ov; bi = oi; }
        }
        if (ej == bi && ej != 0x7fffffff) {   // unique winner lane
            vals[(size_t)r * K_SEL + n_in + t] = ev;
            idxs[(size_t)r * K_SEL + n_in + t] = ej;
            ev = -__builtin_inff(); ej = 0x7fffffff;
        }
    }
}

// ---------------- Decoder + sparse scatter (zeros provided by memset node) -------
__global__ __launch_bounds__(256) void dec_kernel(const float* __restrict__ vals,
                                                  const int* __restrict__ idxs,
                                                  const ushort* __restrict__ WdTb,
                                                  const float* __restrict__ bdec,
                                                  float* __restrict__ recon,
                                                  float* __restrict__ sparse) {
    const int wave = threadIdx.x >> 6, lane = threadIdx.x & 63;
    const int r = blockIdx.x * 4 + wave;

    float lv = 0.f; int li = 0;
    if (lane < K_SEL) {
        lv = vals[(size_t)r * K_SEL + lane];
        li = idxs[(size_t)r * K_SEL + lane];
        li = (li < 0) ? 0 : ((li >= D_LAT) ? D_LAT - 1 : li);   // defensive clamp
    }
    // scatter early (sparse already zeroed by the preceding memset node)
    if (lane < K_SEL && lv != 0.f) sparse[(size_t)r * D_LAT + li] = lv;

    float acc[10];
#pragma unroll
    for (int e = 0; e < 10; ++e) acc[e] = bdec[lane + e * 64];

#pragma unroll 4
    for (int k = 0; k < K_SEL; ++k) {
        float vkv = __shfl(lv, k);
        int   jj  = __shfl(li, k);
        const ushort* wr = WdTb + (size_t)jj * D_IN + lane;
#pragma unroll
        for (int e = 0; e < 10; ++e) acc[e] = fmaf(vkv, b2f(wr[e * 64]), acc[e]);
    }
    float* out = recon + (size_t)r * D_IN + lane;
#pragma unroll
    for (int e = 0; e < 10; ++e) out[e * 64] = acc[e];
}

extern "C" void kernel_launch(void* const* d_in, const int* in_sizes, int n_in,
                              void* d_out, int out_size, void* d_ws, size_t ws_size,
                              hipStream_t stream) {
    const float* x     = (const float*)d_in[0];
    const float* W_enc = (const float*)d_in[1];
    const float* b_enc = (const float*)d_in[2];
    const float* W_dec = (const float*)d_in[3];
    const float* b_dec = (const float*)d_in[4];

    float* recon  = (float*)d_out;                                  // [B][640]
    float* sparse = (float*)d_out + (size_t)B_ROWS * D_IN;          // [B][2560]

    // xB (bf16 x, 84MB) parks in recon region; latB (bf16 latents, 336MB) parks in
    // the sparse region (both consumed before the memset/dec stage).
    ushort* xB   = (ushort*)recon;
    ushort* latB = (ushort*)sparse;

    char* ws = (char*)d_ws;
    size_t off = 0;
    ushort* WdTb = (ushort*)(ws + off); off += (size_t)D_LAT * D_IN * 2;    // 3.28 MB
    ushort* WeB  = (ushort*)(ws + off); off += (size_t)D_LAT * D_IN * 2;    // 3.28 MB
    int*    cidx = (int*)   (ws + off); off += (size_t)B_ROWS * CCAP * 4;   // 16.8 MB
    float*  cval = (float*) (ws + off); off += (size_t)B_ROWS * CCAP * 4;   // 16.8 MB
    int*    ccnt = (int*)   (ws + off); off += (size_t)B_ROWS * 4;          // 0.26 MB
    float*  vals = (float*) (ws + off); off += (size_t)B_ROWS * K_SEL * 4;  // 8.4 MB
    int*    idxs = (int*)   (ws + off);                                     // 8.4 MB

    hipLaunchKernelGGL(cvt_bf16, dim3((size_t)B_ROWS * D_IN / 1024), dim3(256), 0, stream,
                       x, xB);
    hipLaunchKernelGGL(cvt_bf16, dim3((size_t)D_LAT * D_IN / 1024), dim3(256), 0, stream,
                       W_enc, WeB);
    hipLaunchKernelGGL(transpose_wdec, dim3(D_LAT / 32, D_IN / 32), dim3(256), 0, stream,
                       W_dec, WdTb);
    hipLaunchKernelGGL(enc_mfma, dim3(D_LAT / 128, B_ROWS / 128), dim3(256), 0, stream,
                       xB, WeB, b_enc, latB);
    hipLaunchKernelGGL(topk_cand, dim3(B_ROWS / 4), dim3(256), 0, stream,
                       latB, cidx, cval, ccnt);
    // latB (parked in the sparse region) fully consumed; zero the sparse output
    // via the hardware fill path (~6.8 TB/s) so dec_kernel only scatters.
    hipMemsetAsync(sparse, 0, (size_t)B_ROWS * D_LAT * sizeof(float), stream);
    hipLaunchKernelGGL(refine_sel, dim3(B_ROWS / 4), dim3(256), 0, stream,
                       x, W_enc, b_enc, cidx, cval, ccnt, vals, idxs);
    hipLaunchKernelGGL(dec_kernel, dim3(B_ROWS / 4), dim3(256), 0, stream,
                       vals, idxs, WdTb, b_dec, recon, sparse);
}